// Round 1
// 466.338 us; speedup vs baseline: 1.0253x; 1.0253x over previous
//
#include <hip/hip_runtime.h>

#define BATCHN 2
#define SEQL   2048
#define DM     1024
#define DI     2048
#define DSN    16
#define MTOT   (BATCHN * SEQL)   // 4096
#define PADL   (SEQL + 3)        // 2051
#define NC     64                // scan chunks
#define CL     (SEQL / NC)       // 32
#define BCKS   8                 // bc split-K factor

typedef __attribute__((ext_vector_type(8))) __bf16 bf16x8;
typedef __attribute__((ext_vector_type(4))) float f32x4;

__device__ __forceinline__ unsigned short f2b(float f) {
    union { float f; unsigned u; } v; v.f = f;
    unsigned r = v.u + 0x7FFF + ((v.u >> 16) & 1);
    return (unsigned short)(r >> 16);
}
__device__ __forceinline__ float b2f(unsigned short b) {
    union { float f; unsigned u; } v; v.u = ((unsigned)b) << 16;
    return v.f;
}

__device__ __forceinline__ void gl_lds16(const void* g, void* l) {
    __builtin_amdgcn_global_load_lds(
        (const __attribute__((address_space(1))) unsigned int*)g,
        (__attribute__((address_space(3))) unsigned int*)l, 16, 0, 0);
}

// XCD-aware block swizzle: 8 XCDs arranged 2 (x) x 4 (y) over the tile grid;
// each XCD covers a contiguous rectangle. Requires gx%2==0, gy%4==0.
__device__ __forceinline__ void swz(int& bx, int& by) {
    int gx = gridDim.x, gy = gridDim.y;
    int lin = blockIdx.y * gx + blockIdx.x;
    int xcd = lin & 7, k = lin >> 3;
    int rw = gx >> 1, rh = gy >> 2;
    by = (xcd >> 1) * rh + k / rw;
    bx = (xcd & 1) * rw + k % rw;
}

// ---------------- merged convert kernels ----------------
// x [b][l][c] fp32 -> xpad [b][3+l][c] bf16, plus zero the 3 lead rows.
#define NB_XCVT (MTOT * DM / 4 / 256)   // 4096
__global__ void cvt_x_all(const float* __restrict__ src, unsigned short* __restrict__ dst) {
    int blk = blockIdx.x;
    if (blk < NB_XCVT) {
        int i = blk * 256 + threadIdx.x;
        int b = i >> 19;
        float4 v = ((const float4*)src)[i];
        ushort4 o;
        o.x = f2b(v.x); o.y = f2b(v.y); o.z = f2b(v.z); o.w = f2b(v.w);
        ((ushort4*)dst)[i + (b + 1) * (3 * DM / 4)] = o;
    } else {
        int i = (blk - NB_XCVT) * 256 + threadIdx.x;
        if (i < BATCHN * 3 * DM) {
            int b = i / (3 * DM);
            int r = i % (3 * DM);
            dst[(size_t)b * PADL * DM + r] = 0;
        }
    }
}

// All weight converts in one region-dispatched kernel.
#define NB_CONVW (DI * DI / 256)           // 16384
#define NB_TP    ((DM / 32) * (DI / 32))   // 2048
#define NB_IPZ   (DI * DM / 4 / 256)       // 2048
#define NB_DTW   (DI * DI / 4 / 256)       // 4096
#define NB_OW    (DM * DI / 4 / 256)       // 2048
#define NB_BW    (DSN * DI / 4 / 256 + 1)  // 33
__global__ void __launch_bounds__(256)
cvt_w_all(const float* __restrict__ convw, const float* __restrict__ ipw,
          const float* __restrict__ dtw, const float* __restrict__ ow,
          const float* __restrict__ bw, const float* __restrict__ cw,
          unsigned short* __restrict__ wk, unsigned short* __restrict__ Pt,
          unsigned short* __restrict__ ipz, unsigned short* __restrict__ dtwb,
          unsigned short* __restrict__ owb, unsigned short* __restrict__ bcb)
{
    __shared__ float tile[32][33];
    int blk = blockIdx.x;
    int t = threadIdx.x;
    if (blk < NB_CONVW) {
        int i = blk * 256 + t;
        float4 v = ((const float4*)convw)[i];
        wk[0 * (size_t)DI * DI + i] = f2b(v.x);
        wk[1 * (size_t)DI * DI + i] = f2b(v.y);
        wk[2 * (size_t)DI * DI + i] = f2b(v.z);
        wk[3 * (size_t)DI * DI + i] = f2b(v.w);
        return;
    }
    blk -= NB_CONVW;
    if (blk < NB_TP) {
        int ct = (blk & 31) * 32, it = (blk >> 5) * 32;
        int tx = t & 31, ty = t >> 5;   // 32 x 8
#pragma unroll
        for (int r = 0; r < 4; ++r)
            tile[ty + r * 8][tx] = ipw[(size_t)(it + ty + r * 8) * DM + ct + tx];
        __syncthreads();
#pragma unroll
        for (int r = 0; r < 4; ++r)
            Pt[(size_t)(ct + ty + r * 8) * DI + it + tx] = f2b(tile[tx][ty + r * 8]);
        return;
    }
    blk -= NB_TP;
    const float* src;
    unsigned short* dst;
    int n4;
    if (blk < NB_IPZ) {
        src = ipw + (size_t)DI * DM; dst = ipz; n4 = DI * DM / 4;
    } else if ((blk -= NB_IPZ) < NB_DTW) {
        src = dtw; dst = dtwb; n4 = DI * DI / 4;
    } else if ((blk -= NB_DTW) < NB_OW) {
        src = ow; dst = owb; n4 = DM * DI / 4;
    } else if ((blk -= NB_OW) < NB_BW) {
        src = bw; dst = bcb; n4 = DSN * DI / 4;
    } else {
        blk -= NB_BW;
        src = cw; dst = bcb + (size_t)DSN * DI; n4 = DSN * DI / 4;
    }
    int i = blk * 256 + t;
    if (i < n4) {
        float4 v = ((const float4*)src)[i];
        ushort4 o;
        o.x = f2b(v.x); o.y = f2b(v.y); o.z = f2b(v.z); o.w = f2b(v.w);
        ((ushort4*)dst)[i] = o;
    }
}

// ---------------- legacy 128x128 MFMA GEMM (kept for MODE 3 = out-proj) ----
// NOTE: modes 0/1/2/4 are superseded by gemm8 below (and mode-1/4 mk layout
// changed to Mbig), do not launch them from this kernel anymore.
template<int MODE>
__global__ void __launch_bounds__(256)
gemm_bt(const unsigned short* __restrict__ Abase,
        const unsigned short* __restrict__ Bbase,
        const float* __restrict__ bias,
        unsigned short* __restrict__ out_bf,
        float* __restrict__ out_f,
        int K)
{
    __shared__ __align__(16) unsigned short As[128 * 64];
    __shared__ __align__(16) unsigned short Bs[128 * 64];

    const int t = threadIdx.x;
    const int lane = t & 63;
    const int wave = t >> 6;
    const int wm = wave & 1, wn = wave >> 1;
    int bx, by;
    swz(bx, by);
    const int m0 = by * 128, n0 = bx * 128;
    const int srow = t >> 3;                          // 0..31
    const int scol = (t & 7) * 8;                     // LDS physical col (bf16)
    const int gcol = (((t & 7) ^ (srow & 7))) * 8;    // swizzled global col

    f32x4 acc[4][4];
#pragma unroll
    for (int i = 0; i < 4; ++i)
#pragma unroll
        for (int j = 0; j < 4; ++j)
            acc[i][j] = f32x4{0.f, 0.f, 0.f, 0.f};

    const unsigned short* arow[4];
    const unsigned short* brow[4];
#pragma unroll
    for (int i = 0; i < 4; ++i) {
        int rg = m0 + srow + i * 32;
        arow[i] = Abase + (size_t)rg * K;
        int ng = n0 + srow + i * 32;
        brow[i] = Bbase + (size_t)ng * K;
    }
    for (int k0 = 0; k0 < K; k0 += 64) {
#pragma unroll
        for (int i = 0; i < 4; ++i)
            gl_lds16(arow[i] + k0 + gcol, &As[(size_t)(srow + i * 32) * 64 + scol]);
#pragma unroll
        for (int i = 0; i < 4; ++i)
            gl_lds16(brow[i] + k0 + gcol, &Bs[(size_t)(srow + i * 32) * 64 + scol]);
        __syncthreads();
        const int qa = (lane >> 4) * 8;
        const int am = lane & 15;
        const int sw = (am & 7) << 3;   // XOR swizzle on element col
#pragma unroll
        for (int kk = 0; kk < 64; kk += 32) {
            bf16x8 af[4], bfv[4];
#pragma unroll
            for (int i = 0; i < 4; ++i)
                af[i] = *(const bf16x8*)&As[(wm * 64 + i * 16 + am) * 64 + ((kk + qa) ^ sw)];
#pragma unroll
            for (int j = 0; j < 4; ++j)
                bfv[j] = *(const bf16x8*)&Bs[(wn * 64 + j * 16 + am) * 64 + ((kk + qa) ^ sw)];
#pragma unroll
            for (int i = 0; i < 4; ++i)
#pragma unroll
                for (int j = 0; j < 4; ++j)
                    acc[i][j] = __builtin_amdgcn_mfma_f32_16x16x32_bf16(
                        af[i], bfv[j], acc[i][j], 0, 0, 0);
        }
        __syncthreads();
    }

    const int erow0 = m0 + wm * 64;
    const int ecol0 = n0 + wn * 64 + (lane & 15);
    const int rq = (lane >> 4) * 4;
#pragma unroll
    for (int i = 0; i < 4; ++i) {
#pragma unroll
        for (int j = 0; j < 4; ++j) {
            int col = ecol0 + j * 16;
#pragma unroll
            for (int r = 0; r < 4; ++r) {
                int row = erow0 + i * 16 + rq + r;
                float v = acc[i][j][r];
                if (MODE == 3) {
                    out_f[(size_t)row * DM + col] = v;
                } else {
                    out_bf[(size_t)row * DI + col] = f2b(v);
                }
            }
        }
    }
}

// ---------------- 8-phase counted-vmcnt MFMA GEMM (256x128 tile, 8 waves) ---
// T2 (XOR-swizzled LDS, verified 0-conflict) + T3/T4 (8-phase, counted vmcnt,
// never 0 in loop) + T5 (setprio around MFMA) + T1 (XCD swizzle).
// Tile BM=256, BN=128, BK=64; 8 waves as 4(M) x 2(N), 64x64 out per wave.
// LDS slots per K-tile buffer: A-Mh0 (rows {wm*64+0..31}), A-Mh1 (rows
// {wm*64+32..63}) each 128 rows/16KB/2 gl_lds; B-Nh0/B-Nh1 each 64 rows/1 load.
// Phase order per tile: (Mh,Nh) = (0,0),(0,1),(1,1),(1,0); A frags reused
// across Nh pair, BN1 reused P2->P3.  Stage schedule (slot freed 1+ phases
// earlier, verified reader/writer-disjoint per phase):
//   ph1:odd.AM1 ph2:odd.BN0 ph3:evN.AM0 ph4:evN.BN1 ph5:evN.AM1 ph6:evN.BN0
//   ph7:oddN.AM0 ph8:oddN.BN1;  s_waitcnt vmcnt(3) at end of ph4/ph8 only
//   (3 = loads of the 2 most recent phases; drains the tile read next).
// MODE 0: z-proj  A=xpad(+3) SA=1024, B=ipz SB=1024, K=1024 -> z_bf
// MODE 1: conv    A=xpad sliding window SA=1024 K=4096, B=Mbig[2048][4096]
// MODE 2: dt      A=u_bf SA=2048, B=dtw SB=2048, K=2048, sigmoid-clip
// MODE 4: mk-fuse A=wk plane z SA=2048, B=Pt SB=2048, K=2048 -> Mbig layout

#define ABUF8(b) ((b) * 16384)
#define BBUF8(b) (32768 + (b) * 8192)

#define STA8(buf, Mh, kt) do { const int kc_ = ((kt) & NTM) << 6; \
    gl_lds16(pAst + (size_t)((Mh) * 32) * SA + kc_, &lds[ABUF8(buf) + (Mh) * 8192 + ldsw]); \
    gl_lds16(pAst + (size_t)((Mh) * 32 + 128) * SA + kc_, &lds[ABUF8(buf) + (Mh) * 8192 + 4096 + ldsw]); \
} while (0)
#define STB8(buf, Nh, kt) do { const int kc_ = ((kt) & NTM) << 6; \
    gl_lds16(pBst + (size_t)((Nh) * 32) * SB + kc_, &lds[BBUF8(buf) + (Nh) * 4096 + ldsw]); \
} while (0)

#define LA8(buf, Mh) \
    a00 = *(const bf16x8*)&lds[ABUF8(buf) + (Mh) * 8192 + ar + c0]; \
    a01 = *(const bf16x8*)&lds[ABUF8(buf) + (Mh) * 8192 + ar + c1]; \
    a10 = *(const bf16x8*)&lds[ABUF8(buf) + (Mh) * 8192 + ar + 1024 + c0]; \
    a11 = *(const bf16x8*)&lds[ABUF8(buf) + (Mh) * 8192 + ar + 1024 + c1];
#define LB8(buf, Nh) \
    b00 = *(const bf16x8*)&lds[BBUF8(buf) + (Nh) * 4096 + br + c0]; \
    b01 = *(const bf16x8*)&lds[BBUF8(buf) + (Nh) * 4096 + br + c1]; \
    b10 = *(const bf16x8*)&lds[BBUF8(buf) + (Nh) * 4096 + br + 1024 + c0]; \
    b11 = *(const bf16x8*)&lds[BBUF8(buf) + (Nh) * 4096 + br + 1024 + c1];

#define MM8(Mh, Nh) \
    acc[(Mh)*2][(Nh)*2]     = __builtin_amdgcn_mfma_f32_16x16x32_bf16(a00, b00, acc[(Mh)*2][(Nh)*2], 0, 0, 0); \
    acc[(Mh)*2][(Nh)*2+1]   = __builtin_amdgcn_mfma_f32_16x16x32_bf16(a00, b10, acc[(Mh)*2][(Nh)*2+1], 0, 0, 0); \
    acc[(Mh)*2+1][(Nh)*2]   = __builtin_amdgcn_mfma_f32_16x16x32_bf16(a10, b00, acc[(Mh)*2+1][(Nh)*2], 0, 0, 0); \
    acc[(Mh)*2+1][(Nh)*2+1] = __builtin_amdgcn_mfma_f32_16x16x32_bf16(a10, b10, acc[(Mh)*2+1][(Nh)*2+1], 0, 0, 0); \
    acc[(Mh)*2][(Nh)*2]     = __builtin_amdgcn_mfma_f32_16x16x32_bf16(a01, b01, acc[(Mh)*2][(Nh)*2], 0, 0, 0); \
    acc[(Mh)*2][(Nh)*2+1]   = __builtin_amdgcn_mfma_f32_16x16x32_bf16(a01, b11, acc[(Mh)*2][(Nh)*2+1], 0, 0, 0); \
    acc[(Mh)*2+1][(Nh)*2]   = __builtin_amdgcn_mfma_f32_16x16x32_bf16(a11, b01, acc[(Mh)*2+1][(Nh)*2], 0, 0, 0); \
    acc[(Mh)*2+1][(Nh)*2+1] = __builtin_amdgcn_mfma_f32_16x16x32_bf16(a11, b11, acc[(Mh)*2+1][(Nh)*2+1], 0, 0, 0);

#define PH_MID \
    __builtin_amdgcn_s_barrier(); \
    asm volatile("s_waitcnt lgkmcnt(0)" ::: "memory"); \
    __builtin_amdgcn_sched_barrier(0); \
    __builtin_amdgcn_s_setprio(1);
#define PH_END \
    __builtin_amdgcn_s_setprio(0); \
    __builtin_amdgcn_s_barrier(); \
    __builtin_amdgcn_sched_barrier(0);
#define PH_END_W \
    __builtin_amdgcn_s_setprio(0); \
    asm volatile("s_waitcnt vmcnt(3)" ::: "memory"); \
    __builtin_amdgcn_s_barrier(); \
    __builtin_amdgcn_sched_barrier(0);

template<int MODE>
__global__ void __launch_bounds__(512, 1)
gemm8(const unsigned short* __restrict__ Abase,
      const unsigned short* __restrict__ Bbase,
      const float* __restrict__ bias,
      unsigned short* __restrict__ out_bf,
      float* __restrict__ out_f)
{
    constexpr int K   = (MODE == 0) ? 1024 : (MODE == 1) ? 4096 : 2048;
    constexpr int SA  = (MODE == 2 || MODE == 4) ? 2048 : 1024;
    constexpr int SB  = (MODE == 0) ? 1024 : (MODE == 1) ? 4096 : 2048;
    constexpr int NT  = K / 64;
    constexpr int NTM = NT - 1;
    constexpr int NI  = NT / 2;
    (void)out_f;

    __shared__ __align__(16) unsigned short lds[49152];   // 96 KiB: A dbuf 2x32K, B dbuf 2x16K

    const int t = threadIdx.x;
    const int lane = t & 63;
    const int wave = t >> 6;       // 0..7
    const int wm = wave >> 1;      // 0..3 (M quarters, 64 rows each)
    const int wn = wave & 1;       // 0..1 (N halves, 64 cols each)
    int bx, by;
    swz(bx, by);
    const int m0 = by * 256, n0 = bx * 128;

    const unsigned short* Ap;
    if (MODE == 0)      Ap = Abase + ((size_t)(m0 >> 11) * PADL + 3 + (m0 & 2047)) * DM;
    else if (MODE == 1) Ap = Abase + ((size_t)(m0 >> 11) * PADL + (m0 & 2047)) * DM;
    else if (MODE == 4) Ap = Abase + (size_t)blockIdx.z * DI * DI + (size_t)m0 * SA;
    else                Ap = Abase + (size_t)m0 * SA;
    const unsigned short* Bp = Bbase + (size_t)n0 * SB;

    // staging precompute: thread t covers LDS bytes [t*16, t*16+16) of its slot
    const int tr = t >> 3;                                  // 0..63
    const int rowg = ((tr >> 5) << 6) + (tr & 31);          // slot row -> tile row
    const int gcolb = ((t & 7) ^ (tr & 7)) << 3;            // inverse-swizzled src col
    const unsigned short* pAst = Ap + (size_t)rowg * SA + gcolb;
    const unsigned short* pBst = Bp + (size_t)rowg * SB + gcolb;
    const int ldsw = t * 8;

    // fragment-read precompute
    const int am = lane & 15;
    const int qa = (lane >> 4) << 3;
    const int sw = (am & 7) << 3;
    const int c0 = qa ^ sw;            // kk=0 swizzled col
    const int c1 = (32 + qa) ^ sw;     // kk=32 swizzled col
    const int ar = wm * 2048 + am * 64;
    const int br = wn * 2048 + am * 64;

    f32x4 acc[4][4];
#pragma unroll
    for (int i = 0; i < 4; ++i)
#pragma unroll
        for (int j = 0; j < 4; ++j)
            acc[i][j] = f32x4{0.f, 0.f, 0.f, 0.f};

    bf16x8 a00, a01, a10, a11, b00, b01, b10, b11;

    // prologue: T0 complete (6 loads) + T1.AM0,T1.BN1 (3 loads); drain T0.
    STA8(0, 0, 0); STB8(0, 1, 0); STA8(0, 1, 0); STB8(0, 0, 0);
    STA8(1, 0, 1); STB8(1, 1, 1);
    asm volatile("s_waitcnt vmcnt(3)" ::: "memory");
    __builtin_amdgcn_s_barrier();
    __builtin_amdgcn_sched_barrier(0);

#pragma unroll 1
    for (int it = 0; it < NI; ++it) {
        const int ko  = 2 * it + 1;
        const int ke  = (2 * it + 2) & NTM;
        const int ko2 = (2 * it + 3) & NTM;
        // ---- even tile (buf0) ----
        LA8(0, 0) LB8(0, 0) STA8(1, 1, ko);      // P1 (0,0)
        PH_MID MM8(0, 0) PH_END
        LB8(0, 1) STB8(1, 0, ko);                // P2 (0,1) reuse A
        PH_MID MM8(0, 1) PH_END
        LA8(0, 1) STA8(0, 0, ke);                // P3 (1,1) reuse B
        PH_MID MM8(1, 1) PH_END
        LB8(0, 0) STB8(0, 1, ke);                // P4 (1,0) reuse A
        PH_MID MM8(1, 0) PH_END_W
        // ---- odd tile (buf1) ----
        LA8(1, 0) LB8(1, 0) STA8(0, 1, ke);      // P5 (0,0)
        PH_MID MM8(0, 0) PH_END
        LB8(1, 1) STB8(0, 0, ke);                // P6 (0,1)
        PH_MID MM8(0, 1) PH_END
        LA8(1, 1) STA8(1, 0, ko2);               // P7 (1,1)
        PH_MID MM8(1, 1) PH_END
        LB8(1, 0) STB8(1, 1, ko2);               // P8 (1,0)
        PH_MID MM8(1, 0) PH_END_W
    }

    asm volatile("s_waitcnt vmcnt(0)" ::: "memory");  // drain trailing stages

    // epilogue: row = m0 + wm*64 + mi*16 + (lane>>4)*4 + r ; col = n0 + wn*64 + nj*16 + am
    const int rq = (lane >> 4) << 2;
    const int er = m0 + wm * 64;
    const int ec = n0 + wn * 64 + am;
#pragma unroll
    for (int mi = 0; mi < 4; ++mi) {
#pragma unroll
        for (int nj = 0; nj < 4; ++nj) {
            int col = ec + nj * 16;
#pragma unroll
            for (int r = 0; r < 4; ++r) {
                int row = er + mi * 16 + rq + r;
                float v = acc[mi][nj][r];
                if (MODE == 0) {
                    out_bf[(size_t)row * DI + col] = f2b(v);
                } else if (MODE == 1) {
                    v += bias[col];
                    out_bf[(size_t)row * DI + col] = f2b(v);
                } else if (MODE == 2) {
                    v += bias[col];
                    float s = 1.f / (1.f + __expf(-v));
                    s = fminf(fmaxf(s, 1e-4f), 1.f);
                    out_bf[(size_t)row * DI + col] = f2b(s);
                } else { // MODE 4: Mbig[o][z*1024 + cm]
                    out_bf[(size_t)row * 4096 + (size_t)blockIdx.z * 1024 + col] = f2b(v);
                }
            }
        }
    }
}

// ---------------- B/C projection: MFMA split-K ----------------
__global__ void __launch_bounds__(256)
bc_mfma(const unsigned short* __restrict__ u,
        const unsigned short* __restrict__ w,
        float* __restrict__ pc)
{
    const int t = threadIdx.x;
    const int lane = t & 63;
    const int wave = t >> 6;
    const int ks = blockIdx.x;                    // 0..BCKS-1
    const int m0 = blockIdx.y * 128 + wave * 32;
    const int am = lane & 15, quad = lane >> 4;

    f32x4 acc[2][2];
#pragma unroll
    for (int i = 0; i < 2; ++i)
#pragma unroll
        for (int j = 0; j < 2; ++j)
            acc[i][j] = f32x4{0.f, 0.f, 0.f, 0.f};

    const int kbase = ks * (DI / BCKS);
    const unsigned short* ur0 = u + (size_t)(m0 + am) * DI;
    const unsigned short* ur1 = u + (size_t)(m0 + 16 + am) * DI;
    const unsigned short* wr0 = w + (size_t)am * DI;
    const unsigned short* wr1 = w + (size_t)(16 + am) * DI;
#pragma unroll 2
    for (int kk = 0; kk < DI / BCKS; kk += 32) {
        int k = kbase + kk + quad * 8;
        bf16x8 a0 = *(const bf16x8*)(ur0 + k);
        bf16x8 a1 = *(const bf16x8*)(ur1 + k);
        bf16x8 b0 = *(const bf16x8*)(wr0 + k);
        bf16x8 b1 = *(const bf16x8*)(wr1 + k);
        acc[0][0] = __builtin_amdgcn_mfma_f32_16x16x32_bf16(a0, b0, acc[0][0], 0, 0, 0);
        acc[0][1] = __builtin_amdgcn_mfma_f32_16x16x32_bf16(a0, b1, acc[0][1], 0, 0, 0);
        acc[1][0] = __builtin_amdgcn_mfma_f32_16x16x32_bf16(a1, b0, acc[1][0], 0, 0, 0);
        acc[1][1] = __builtin_amdgcn_mfma_f32_16x16x32_bf16(a1, b1, acc[1][1], 0, 0, 0);
    }
    float* base = pc + (size_t)ks * MTOT * 32;
#pragma unroll
    for (int i = 0; i < 2; ++i)
#pragma unroll
        for (int j = 0; j < 2; ++j)
#pragma unroll
            for (int r = 0; r < 4; ++r) {
                int row = m0 + i * 16 + quad * 4 + r;
                int col = j * 16 + am;
                base[(size_t)row * 32 + col] = acc[i][j][r];
            }
}

__global__ void __launch_bounds__(256)
bc_reduce(const float* __restrict__ pc, float* __restrict__ outf)
{
    int i = blockIdx.x * 256 + threadIdx.x;       // float4 index, 32768 total
    const float4* p4 = (const float4*)pc;
    float4 s = p4[i];
#pragma unroll
    for (int ks = 1; ks < BCKS; ++ks) {
        float4 v = p4[(size_t)ks * (MTOT * 8) + i];
        s.x += v.x; s.y += v.y; s.z += v.z; s.w += v.w;
    }
    ((float4*)outf)[i] = s;
}

// ---------------- chunked selective scan ----------------
__global__ void __launch_bounds__(256)
scan_p1(const unsigned short* __restrict__ dt_bf,
        const unsigned short* __restrict__ u_bf,
        const float* __restrict__ bcf,
        const float* __restrict__ A_log,
        float* __restrict__ Pbuf,
        float* __restrict__ Sbuf)
{
    const int t = threadIdx.x;
    const int blk = blockIdx.x;          // 1024 = c(64) x dh(8) x b(2)
    const int c  = blk & (NC - 1);
    const int dh = (blk >> 6) & 7;
    const int b  = blk >> 9;
    const int d  = dh * 256 + t;

    float Adn[16];
    {
        const float4* ar = (const float4*)(A_log + (size_t)d * DSN);
#pragma unroll
        for (int q = 0; q < 4; ++q) {
            float4 v = ar[q];
            Adn[q * 4 + 0] = -__expf(v.x);
            Adn[q * 4 + 1] = -__expf(v.y);
            Adn[q * 4 + 2] = -__expf(v.z);
            Adn[q * 4 + 3] = -__expf(v.w);
        }
    }
    float s[16], P[16];
#pragma unroll
    for (int n = 0; n < 16; ++n) { s[n] = 0.f; P[n] = 1.f; }

    const size_t rowbase = (size_t)b * SEQL + (size_t)c * CL;
    for (int l0 = 0; l0 < CL; l0 += 4) {
        float dt4[4], u4[4];
#pragma unroll
        for (int j = 0; j < 4; ++j) {
            size_t rb = rowbase + l0 + j;
            dt4[j] = b2f(dt_bf[rb * DI + d]);
            u4[j] = b2f(u_bf[rb * DI + d]);
        }
#pragma unroll
        for (int j = 0; j < 4; ++j) {
            size_t rb = rowbase + l0 + j;
            const float4* Br = (const float4*)(bcf + rb * 32);
            float Bn[16];
#pragma unroll
            for (int q = 0; q < 4; ++q) {
                float4 v = Br[q];
                Bn[q * 4 + 0] = v.x; Bn[q * 4 + 1] = v.y;
                Bn[q * 4 + 2] = v.z; Bn[q * 4 + 3] = v.w;
            }
            float dt = dt4[j];
            float dBu = dt * u4[j];
#pragma unroll
            for (int n = 0; n < 16; ++n) {
                float x = dt * Adn[n];
                x = fminf(fmaxf(x, -5.f), 5.f);
                float dA = __expf(x);
                P[n] *= dA;
                s[n] = dA * s[n] + (dBu * Bn[n] + 1e-6f);
            }
        }
    }
    size_t ob = (((size_t)c * BATCHN + b) * DI + d) * DSN;
#pragma unroll
    for (int q = 0; q < 4; ++q) {
        ((float4*)(Pbuf + ob))[q] = make_float4(P[q*4], P[q*4+1], P[q*4+2], P[q*4+3]);
        ((float4*)(Sbuf + ob))[q] = make_float4(s[q*4], s[q*4+1], s[q*4+2], s[q*4+3]);
    }
}

__global__ void __launch_bounds__(256)
scan_p2(const float* __restrict__ Pbuf,
        const float* __restrict__ Sbuf,
        float* __restrict__ Ibuf)
{
    const int i = blockIdx.x * 256 + threadIdx.x;  // (b*DI+d)*16+n, 65536
    const int stride = BATCHN * DI * DSN;          // 65536
    float s = 0.f;
    for (int c0 = 0; c0 < NC; c0 += 8) {
        float Pv[8], Sv[8];
#pragma unroll
        for (int j = 0; j < 8; ++j) {
            size_t idx = (size_t)(c0 + j) * stride + i;
            Pv[j] = Pbuf[idx];
            Sv[j] = Sbuf[idx];
        }
#pragma unroll
        for (int j = 0; j < 8; ++j) {
            size_t idx = (size_t)(c0 + j) * stride + i;
            Ibuf[idx] = s;
            s = Pv[j] * s + Sv[j];
        }
    }
}

__global__ void __launch_bounds__(256)
scan_p3(const unsigned short* __restrict__ dt_bf,
        const unsigned short* __restrict__ u_bf,
        const float* __restrict__ bcf,
        const unsigned short* __restrict__ z_bf,
        const float* __restrict__ A_log,
        const float* __restrict__ Dvec,
        const float* __restrict__ Ibuf,
        unsigned short* __restrict__ y_bf)
{
    const int t = threadIdx.x;
    const int blk = blockIdx.x;
    const int c  = blk & (NC - 1);
    const int dh = (blk >> 6) & 7;
    const int b  = blk >> 9;
    const int d  = dh * 256 + t;

    float Adn[16];
    {
        const float4* ar = (const float4*)(A_log + (size_t)d * DSN);
#pragma unroll
        for (int q = 0; q < 4; ++q) {
            float4 v = ar[q];
            Adn[q * 4 + 0] = -__expf(v.x);
            Adn[q * 4 + 1] = -__expf(v.y);
            Adn[q * 4 + 2] = -__expf(v.z);
            Adn[q * 4 + 3] = -__expf(v.w);
        }
    }
    const float Dd = Dvec[d];
    float s[16];
    {
        size_t ib = (((size_t)c * BATCHN + b) * DI + d) * DSN;
#pragma unroll
        for (int q = 0; q < 4; ++q) {
            float4 v = ((const float4*)(Ibuf + ib))[q];
            s[q * 4 + 0] = v.x; s[q * 4 + 1] = v.y;
            s[q * 4 + 2] = v.z; s[q * 4 + 3] = v.w;
        }
    }

    const size_t rowbase = (size_t)b * SEQL + (size_t)c * CL;
    for (int l0 = 0; l0 < CL; l0 += 4) {
        float dt4[4], u4[4], z4[4];
#pragma unroll
        for (int j = 0; j < 4; ++j) {
            size_t rb = rowbase + l0 + j;
            dt4[j] = b2f(dt_bf[rb * DI + d]);
            u4[j] = b2f(u_bf[rb * DI + d]);
            z4[j] = b2f(z_bf[rb * DI + d]);
        }
#pragma unroll
        for (int j = 0; j < 4; ++j) {
            size_t rb = rowbase + l0 + j;
            const float4* Br = (const float4*)(bcf + rb * 32);
            float Bn[16], Cn[16];
#pragma unroll
            for (int q = 0; q < 4; ++q) {
                float4 v = Br[q];
                Bn[q * 4 + 0] = v.x; Bn[q * 4 + 1] = v.y;
                Bn[q * 4 + 2] = v.z; Bn[q * 4 + 3] = v.w;
                float4 w = Br[q + 4];
                Cn[q * 4 + 0] = w.x; Cn[q * 4 + 1] = w.y;
                Cn[q * 4 + 2] = w.z; Cn[q * 4 + 3] = w.w;
            }
            float dt = dt4[j];
            float dBu = dt * u4[j];
            float y = 0.f;
#pragma unroll
            for (int n = 0; n < 16; ++n) {
                float x = dt * Adn[n];
                x = fminf(fmaxf(x, -5.f), 5.f);
                float dA = __expf(x);
                s[n] = dA * s[n] + (dBu * Bn[n] + 1e-6f);
                y += s[n] * Cn[n];
            }
            y += Dd * u4[j];
            float zz = z4[j];
            y *= zz / (1.f + __expf(-zz));
            y_bf[rb * DI + d] = f2b(y);
        }
    }
}

// ---------------- launch ----------------
extern "C" void kernel_launch(void* const* d_in, const int* in_sizes, int n_in,
                              void* d_out, int out_size, void* d_ws, size_t ws_size,
                              hipStream_t stream) {
    const float* x     = (const float*)d_in[0];
    const float* ipw   = (const float*)d_in[1];
    const float* convw = (const float*)d_in[2];
    const float* convb = (const float*)d_in[3];
    const float* dtw   = (const float*)d_in[4];
    const float* dtb   = (const float*)d_in[5];
    const float* alog  = (const float*)d_in[6];
    const float* dvec  = (const float*)d_in[7];
    const float* bw    = (const float*)d_in[8];
    const float* cwm   = (const float*)d_in[9];
    const float* ow    = (const float*)d_in[10];
    float* out = (float*)d_out;

    char* ws = (char*)d_ws;
    size_t off = 0;
    auto carve = [&](size_t bytes) {
        char* p = ws + off;
        off += (bytes + 255) & ~(size_t)255;
        return p;
    };
    unsigned short* xpad   = (unsigned short*)carve((size_t)BATCHN * PADL * DM * 2);
    unsigned short* ipz_bf = (unsigned short*)carve((size_t)DI * DM * 2);
    unsigned short* Pt_bf  = (unsigned short*)carve((size_t)DM * DI * 2);
    unsigned short* wk_bf  = (unsigned short*)carve((size_t)4 * DI * DI * 2);
    unsigned short* mk_bf  = (unsigned short*)carve((size_t)4 * DI * DM * 2);  // Mbig [2048][4096]
    unsigned short* dtw_bf = (unsigned short*)carve((size_t)DI * DI * 2);
    unsigned short* ow_bf  = (unsigned short*)carve((size_t)DM * DI * 2);
    unsigned short* bc_bf  = (unsigned short*)carve((size_t)2 * DSN * DI * 2);
    unsigned short* z_bf   = (unsigned short*)carve((size_t)MTOT * DI * 2);
    unsigned short* u_bf   = (unsigned short*)carve((size_t)MTOT * DI * 2);
    unsigned short* dt_bf  = (unsigned short*)carve((size_t)MTOT * DI * 2);
    float*          bc_f   = (float*)carve((size_t)MTOT * 2 * DSN * 4);
    unsigned short* y_bf   = (unsigned short*)carve((size_t)MTOT * DI * 2);
    float*          Pbuf   = (float*)carve((size_t)NC * BATCHN * DI * DSN * 4);
    float*          Sbuf   = (float*)carve((size_t)NC * BATCHN * DI * DSN * 4);
    float*          Ibuf   = (float*)carve((size_t)NC * BATCHN * DI * DSN * 4);
    float*          pc_f   = (float*)carve((size_t)BCKS * MTOT * 32 * 4);

    // converts (2 kernels)
    cvt_x_all<<<NB_XCVT + (BATCHN * 3 * DM + 255) / 256, 256, 0, stream>>>(x, xpad);
    {
        int nb = NB_CONVW + NB_TP + NB_IPZ + NB_DTW + NB_OW + 2 * NB_BW;
        cvt_w_all<<<nb, 256, 0, stream>>>(convw, ipw, dtw, ow, bw, cwm,
                                          wk_bf, Pt_bf, ipz_bf, dtw_bf, ow_bf, bc_bf);
    }

    // mk-fuse: Mbig[o][z*1024+cm] = (W_z @ P)[o][cm]
    gemm8<4><<<dim3(8, 8, 4), 512, 0, stream>>>(wk_bf, Pt_bf, nullptr, mk_bf, nullptr);
    // z-proj: z = x @ ipz^T
    gemm8<0><<<dim3(16, 16), 512, 0, stream>>>(xpad, ipz_bf, nullptr, z_bf, nullptr);
    // conv (fused, single K=4096 GEMM over xpad sliding window x Mbig^T)
    gemm8<1><<<dim3(16, 16), 512, 0, stream>>>(xpad, mk_bf, convb, u_bf, nullptr);
    // B/C projection: MFMA split-K + reduce
    bc_mfma<<<dim3(BCKS, MTOT / 128), 256, 0, stream>>>(u_bf, bc_bf, pc_f);
    bc_reduce<<<MTOT * 32 / 4 / 256, 256, 0, stream>>>(pc_f, bc_f);
    // dt projection + sigmoid/clip -> bf16
    gemm8<2><<<dim3(16, 16), 512, 0, stream>>>(u_bf, dtw_bf, dtb, dt_bf, nullptr);
    // chunked scan
    scan_p1<<<BATCHN * 8 * NC, 256, 0, stream>>>(dt_bf, u_bf, bc_f, alog, Pbuf, Sbuf);
    scan_p2<<<BATCHN * DI * DSN / 256, 256, 0, stream>>>(Pbuf, Sbuf, Ibuf);
    scan_p3<<<BATCHN * 8 * NC, 256, 0, stream>>>(dt_bf, u_bf, bc_f, z_bf, alog, dvec, Ibuf, y_bf);
    // out projection (kept on 128^2 kernel: 256 blocks at that tile)
    gemm_bt<3><<<dim3(8, 32), 256, 0, stream>>>(y_bf, ow_bf, nullptr, nullptr, out, DI);
}

// Round 2
// 466.335 us; speedup vs baseline: 1.0253x; 1.0000x over previous
//
#include <hip/hip_runtime.h>

#define BATCHN 2
#define SEQL   2048
#define DM     1024
#define DI     2048
#define DSN    16
#define MTOT   (BATCHN * SEQL)   // 4096
#define PADL   (SEQL + 3)        // 2051
#define NC     64                // scan chunks
#define CL     (SEQL / NC)       // 32
#define BCKS   8                 // bc split-K factor

typedef __attribute__((ext_vector_type(8))) __bf16 bf16x8;
typedef __attribute__((ext_vector_type(4))) float f32x4;

__device__ __forceinline__ unsigned short f2b(float f) {
    union { float f; unsigned u; } v; v.f = f;
    unsigned r = v.u + 0x7FFF + ((v.u >> 16) & 1);
    return (unsigned short)(r >> 16);
}
__device__ __forceinline__ float b2f(unsigned short b) {
    union { float f; unsigned u; } v; v.u = ((unsigned)b) << 16;
    return v.f;
}

__device__ __forceinline__ void gl_lds16(const void* g, void* l) {
    __builtin_amdgcn_global_load_lds(
        (const __attribute__((address_space(1))) unsigned int*)g,
        (__attribute__((address_space(3))) unsigned int*)l, 16, 0, 0);
}

// XCD-aware block swizzle: 8 XCDs arranged 2 (x) x 4 (y) over the tile grid;
// each XCD covers a contiguous rectangle. Requires gx%2==0, gy%4==0.
__device__ __forceinline__ void swz(int& bx, int& by) {
    int gx = gridDim.x, gy = gridDim.y;
    int lin = blockIdx.y * gx + blockIdx.x;
    int xcd = lin & 7, k = lin >> 3;
    int rw = gx >> 1, rh = gy >> 2;
    by = (xcd >> 1) * rh + k / rw;
    bx = (xcd & 1) * rw + k % rw;
}

// ---------------- merged convert kernels ----------------
// x [b][l][c] fp32 -> xpad [b][3+l][c] bf16, plus zero the 3 lead rows.
#define NB_XCVT (MTOT * DM / 4 / 256)   // 4096
__global__ void cvt_x_all(const float* __restrict__ src, unsigned short* __restrict__ dst) {
    int blk = blockIdx.x;
    if (blk < NB_XCVT) {
        int i = blk * 256 + threadIdx.x;
        int b = i >> 19;
        float4 v = ((const float4*)src)[i];
        ushort4 o;
        o.x = f2b(v.x); o.y = f2b(v.y); o.z = f2b(v.z); o.w = f2b(v.w);
        ((ushort4*)dst)[i + (b + 1) * (3 * DM / 4)] = o;
    } else {
        int i = (blk - NB_XCVT) * 256 + threadIdx.x;
        if (i < BATCHN * 3 * DM) {
            int b = i / (3 * DM);
            int r = i % (3 * DM);
            dst[(size_t)b * PADL * DM + r] = 0;
        }
    }
}

// All weight converts in one region-dispatched kernel.
#define NB_CONVW (DI * DI / 256)           // 16384
#define NB_TP    ((DM / 32) * (DI / 32))   // 2048
#define NB_IPZ   (DI * DM / 4 / 256)       // 2048
#define NB_DTW   (DI * DI / 4 / 256)       // 4096
#define NB_OW    (DM * DI / 4 / 256)       // 2048
#define NB_BW    (DSN * DI / 4 / 256 + 1)  // 33
__global__ void __launch_bounds__(256)
cvt_w_all(const float* __restrict__ convw, const float* __restrict__ ipw,
          const float* __restrict__ dtw, const float* __restrict__ ow,
          const float* __restrict__ bw, const float* __restrict__ cw,
          unsigned short* __restrict__ wk, unsigned short* __restrict__ Pt,
          unsigned short* __restrict__ ipz, unsigned short* __restrict__ dtwb,
          unsigned short* __restrict__ owb, unsigned short* __restrict__ bcb)
{
    __shared__ float tile[32][33];
    int blk = blockIdx.x;
    int t = threadIdx.x;
    if (blk < NB_CONVW) {
        int i = blk * 256 + t;
        float4 v = ((const float4*)convw)[i];
        wk[0 * (size_t)DI * DI + i] = f2b(v.x);
        wk[1 * (size_t)DI * DI + i] = f2b(v.y);
        wk[2 * (size_t)DI * DI + i] = f2b(v.z);
        wk[3 * (size_t)DI * DI + i] = f2b(v.w);
        return;
    }
    blk -= NB_CONVW;
    if (blk < NB_TP) {
        int ct = (blk & 31) * 32, it = (blk >> 5) * 32;
        int tx = t & 31, ty = t >> 5;   // 32 x 8
#pragma unroll
        for (int r = 0; r < 4; ++r)
            tile[ty + r * 8][tx] = ipw[(size_t)(it + ty + r * 8) * DM + ct + tx];
        __syncthreads();
#pragma unroll
        for (int r = 0; r < 4; ++r)
            Pt[(size_t)(ct + ty + r * 8) * DI + it + tx] = f2b(tile[tx][ty + r * 8]);
        return;
    }
    blk -= NB_TP;
    const float* src;
    unsigned short* dst;
    int n4;
    if (blk < NB_IPZ) {
        src = ipw + (size_t)DI * DM; dst = ipz; n4 = DI * DM / 4;
    } else if ((blk -= NB_IPZ) < NB_DTW) {
        src = dtw; dst = dtwb; n4 = DI * DI / 4;
    } else if ((blk -= NB_DTW) < NB_OW) {
        src = ow; dst = owb; n4 = DM * DI / 4;
    } else if ((blk -= NB_OW) < NB_BW) {
        src = bw; dst = bcb; n4 = DSN * DI / 4;
    } else {
        blk -= NB_BW;
        src = cw; dst = bcb + (size_t)DSN * DI; n4 = DSN * DI / 4;
    }
    int i = blk * 256 + t;
    if (i < n4) {
        float4 v = ((const float4*)src)[i];
        ushort4 o;
        o.x = f2b(v.x); o.y = f2b(v.y); o.z = f2b(v.z); o.w = f2b(v.w);
        ((ushort4*)dst)[i] = o;
    }
}

// ---------------- legacy 128x128 MFMA GEMM (kept for MODE 3 = out-proj) ----
template<int MODE>
__global__ void __launch_bounds__(256)
gemm_bt(const unsigned short* __restrict__ Abase,
        const unsigned short* __restrict__ Bbase,
        const float* __restrict__ bias,
        unsigned short* __restrict__ out_bf,
        float* __restrict__ out_f,
        int K)
{
    __shared__ __align__(16) unsigned short As[128 * 64];
    __shared__ __align__(16) unsigned short Bs[128 * 64];

    const int t = threadIdx.x;
    const int lane = t & 63;
    const int wave = t >> 6;
    const int wm = wave & 1, wn = wave >> 1;
    int bx, by;
    swz(bx, by);
    const int m0 = by * 128, n0 = bx * 128;
    const int srow = t >> 3;                          // 0..31
    const int scol = (t & 7) * 8;                     // LDS physical col (bf16)
    const int gcol = (((t & 7) ^ (srow & 7))) * 8;    // swizzled global col

    f32x4 acc[4][4];
#pragma unroll
    for (int i = 0; i < 4; ++i)
#pragma unroll
        for (int j = 0; j < 4; ++j)
            acc[i][j] = f32x4{0.f, 0.f, 0.f, 0.f};

    const unsigned short* arow[4];
    const unsigned short* brow[4];
#pragma unroll
    for (int i = 0; i < 4; ++i) {
        int rg = m0 + srow + i * 32;
        arow[i] = Abase + (size_t)rg * K;
        int ng = n0 + srow + i * 32;
        brow[i] = Bbase + (size_t)ng * K;
    }
    for (int k0 = 0; k0 < K; k0 += 64) {
#pragma unroll
        for (int i = 0; i < 4; ++i)
            gl_lds16(arow[i] + k0 + gcol, &As[(size_t)(srow + i * 32) * 64 + scol]);
#pragma unroll
        for (int i = 0; i < 4; ++i)
            gl_lds16(brow[i] + k0 + gcol, &Bs[(size_t)(srow + i * 32) * 64 + scol]);
        __syncthreads();
        const int qa = (lane >> 4) * 8;
        const int am = lane & 15;
        const int sw = (am & 7) << 3;   // XOR swizzle on element col
#pragma unroll
        for (int kk = 0; kk < 64; kk += 32) {
            bf16x8 af[4], bfv[4];
#pragma unroll
            for (int i = 0; i < 4; ++i)
                af[i] = *(const bf16x8*)&As[(wm * 64 + i * 16 + am) * 64 + ((kk + qa) ^ sw)];
#pragma unroll
            for (int j = 0; j < 4; ++j)
                bfv[j] = *(const bf16x8*)&Bs[(wn * 64 + j * 16 + am) * 64 + ((kk + qa) ^ sw)];
#pragma unroll
            for (int i = 0; i < 4; ++i)
#pragma unroll
                for (int j = 0; j < 4; ++j)
                    acc[i][j] = __builtin_amdgcn_mfma_f32_16x16x32_bf16(
                        af[i], bfv[j], acc[i][j], 0, 0, 0);
        }
        __syncthreads();
    }

    const int erow0 = m0 + wm * 64;
    const int ecol0 = n0 + wn * 64 + (lane & 15);
    const int rq = (lane >> 4) * 4;
#pragma unroll
    for (int i = 0; i < 4; ++i) {
#pragma unroll
        for (int j = 0; j < 4; ++j) {
            int col = ecol0 + j * 16;
#pragma unroll
            for (int r = 0; r < 4; ++r) {
                int row = erow0 + i * 16 + rq + r;
                float v = acc[i][j][r];
                if (MODE == 3) {
                    out_f[(size_t)row * DM + col] = v;
                } else {
                    out_bf[(size_t)row * DI + col] = f2b(v);
                }
            }
        }
    }
}

// ---------------- pipelined MFMA GEMM (256x128 tile, 8 waves) -------------
// R2 redesign: the R1 8-phase variant was LDS-read-bound + barrier-exposed
// (MfmaUtil 39%). This version: per K-tile ONE compute cluster (32 MFMA),
// register double-buffered fragments (X/Y sets), 2 barriers per K-tile,
// counted vmcnt(6) staging (2 tiles in flight, never drained in loop).
// Per K-tile per wave: 16 ds_read_b128 (8 A + 8 B, no re-reads) issued
// BEFORE the MFMA cluster of the previous tile -> latency hidden.
// LDS: A dbuf 2x32KB + B dbuf 2x16KB = 96 KiB, XOR-swizzled (0 conflicts).
// MODE 0: z-proj  A=xpad(+3) SA=1024, B=ipz SB=1024, K=1024 -> z_bf
// MODE 1: conv    A=xpad sliding window SA=1024 K=4096, B=Mbig[2048][4096]
// MODE 2: dt      A=u_bf SA=2048, B=dtw SB=2048, K=2048, sigmoid-clip
// MODE 4: mk-fuse A=wk plane z SA=2048, B=Pt SB=2048, K=2048 -> Mbig layout

#define STAGE(buf, kt) do { \
    const int kc_ = ((kt) & NTM) << 6; \
    gl_lds16(pA + 0 * 64 * SA + kc_, &lds[(buf) * 16384 + ldsA + 0 * 4096]); \
    gl_lds16(pA + 1 * 64 * SA + kc_, &lds[(buf) * 16384 + ldsA + 1 * 4096]); \
    gl_lds16(pA + 2 * 64 * SA + kc_, &lds[(buf) * 16384 + ldsA + 2 * 4096]); \
    gl_lds16(pA + 3 * 64 * SA + kc_, &lds[(buf) * 16384 + ldsA + 3 * 4096]); \
    gl_lds16(pB + 0 * 64 * SB + kc_, &lds[32768 + (buf) * 8192 + ldsB + 0 * 4096]); \
    gl_lds16(pB + 1 * 64 * SB + kc_, &lds[32768 + (buf) * 8192 + ldsB + 1 * 4096]); \
} while (0)

#define LOADF(AF, BF, buf) do { \
    const unsigned short* _ab = &lds[(buf) * 16384 + arow]; \
    const unsigned short* _bb = &lds[32768 + (buf) * 8192 + brow]; \
    _Pragma("unroll") \
    for (int _i = 0; _i < 4; ++_i) { \
        AF[_i][0] = *(const bf16x8*)&_ab[_i * 1024 + c0]; \
        AF[_i][1] = *(const bf16x8*)&_ab[_i * 1024 + c1]; \
    } \
    _Pragma("unroll") \
    for (int _j = 0; _j < 4; ++_j) { \
        BF[_j][0] = *(const bf16x8*)&_bb[_j * 1024 + c0]; \
        BF[_j][1] = *(const bf16x8*)&_bb[_j * 1024 + c1]; \
    } \
} while (0)

#define MME(AF, BF) do { \
    _Pragma("unroll") \
    for (int _i = 0; _i < 4; ++_i) \
    _Pragma("unroll") \
    for (int _j = 0; _j < 4; ++_j) { \
        acc[_i][_j] = __builtin_amdgcn_mfma_f32_16x16x32_bf16(AF[_i][0], BF[_j][0], acc[_i][_j], 0, 0, 0); \
        acc[_i][_j] = __builtin_amdgcn_mfma_f32_16x16x32_bf16(AF[_i][1], BF[_j][1], acc[_i][_j], 0, 0, 0); \
    } \
} while (0)

template<int MODE>
__global__ void __launch_bounds__(512, 1)
gemm8(const unsigned short* __restrict__ Abase,
      const unsigned short* __restrict__ Bbase,
      const float* __restrict__ bias,
      unsigned short* __restrict__ out_bf,
      float* __restrict__ out_f)
{
    constexpr int K   = (MODE == 0) ? 1024 : (MODE == 1) ? 4096 : 2048;
    constexpr int SA  = (MODE == 2 || MODE == 4) ? 2048 : 1024;
    constexpr int SB  = (MODE == 0) ? 1024 : (MODE == 1) ? 4096 : 2048;
    constexpr int NT  = K / 64;
    constexpr int NTM = NT - 1;
    constexpr int NI  = NT / 2;
    (void)out_f;

    __shared__ __align__(16) unsigned short lds[49152];   // 96 KiB

    const int t = threadIdx.x;
    const int lane = t & 63;
    const int wave = t >> 6;       // 0..7
    const int wm = wave >> 1;      // 0..3 (M quarters, 64 rows each)
    const int wn = wave & 1;       // 0..1 (N halves, 64 cols each)
    int bx, by;
    swz(bx, by);
    const int m0 = by * 256, n0 = bx * 128;

    const unsigned short* Ap;
    if (MODE == 0)      Ap = Abase + ((size_t)(m0 >> 11) * PADL + 3 + (m0 & 2047)) * DM;
    else if (MODE == 1) Ap = Abase + ((size_t)(m0 >> 11) * PADL + (m0 & 2047)) * DM;
    else if (MODE == 4) Ap = Abase + (size_t)blockIdx.z * DI * DI + (size_t)m0 * SA;
    else                Ap = Abase + (size_t)m0 * SA;
    const unsigned short* Bp = Bbase + (size_t)n0 * SB;

    // staging precompute: thread t covers row strow+s*64, col-granule (t&7)
    const int strow = t >> 3;                           // 0..63
    const int gcs = ((t & 7) ^ (strow & 7)) * 8;        // inverse-swizzled src col (shorts)
    const unsigned short* pA = Ap + (size_t)strow * SA + gcs;
    const unsigned short* pB = Bp + (size_t)strow * SB + gcs;
    const int ldsA = t * 8;                             // short idx; = base + lane*16B (wave-uniform) OK
    const int ldsB = t * 8;

    // fragment-read precompute
    const int am = lane & 15;
    const int qa = (lane >> 4) << 3;
    const int sw = (am & 7) << 3;
    const int c0 = qa ^ sw;            // kk=0 swizzled col (shorts)
    const int c1 = (32 + qa) ^ sw;     // kk=32 swizzled col
    const int arow = (wm * 64 + am) * 64;
    const int brow = (wn * 64 + am) * 64;

    f32x4 acc[4][4];
#pragma unroll
    for (int i = 0; i < 4; ++i)
#pragma unroll
        for (int j = 0; j < 4; ++j)
            acc[i][j] = f32x4{0.f, 0.f, 0.f, 0.f};

    bf16x8 aX[4][2], bX[4][2], aY[4][2], bY[4][2];

    // prologue: stage tiles 0,1; wait tile 0; read frags(0) -> X
    STAGE(0, 0);
    STAGE(1, 1);
    asm volatile("s_waitcnt vmcnt(6)" ::: "memory");
    __builtin_amdgcn_s_barrier();
    __builtin_amdgcn_sched_barrier(0);
    LOADF(aX, bX, 0);

#pragma unroll 1
    for (int it = 0; it < NI; ++it) {
        // ---- even tile 2it: compute X, prefetch frags(2it+1)->Y, stage 2it+2->buf0
        asm volatile("s_waitcnt lgkmcnt(0)" ::: "memory");   // my buf0 frag reads done
        __builtin_amdgcn_s_barrier();                        // all waves: buf0 free
        __builtin_amdgcn_sched_barrier(0);
        STAGE(0, 2 * it + 2);
        asm volatile("s_waitcnt vmcnt(6)" ::: "memory");     // tile 2it+1 staged
        __builtin_amdgcn_s_barrier();                        // all waves: buf1 ready
        __builtin_amdgcn_sched_barrier(0);
        LOADF(aY, bY, 1);                                    // issue, no wait
        __builtin_amdgcn_s_setprio(1);
        MME(aX, bX);
        __builtin_amdgcn_s_setprio(0);
        // ---- odd tile 2it+1: compute Y, prefetch frags(2it+2)->X, stage 2it+3->buf1
        asm volatile("s_waitcnt lgkmcnt(0)" ::: "memory");   // buf1 frag reads done
        __builtin_amdgcn_s_barrier();                        // all waves: buf1 free
        __builtin_amdgcn_sched_barrier(0);
        STAGE(1, 2 * it + 3);
        asm volatile("s_waitcnt vmcnt(6)" ::: "memory");     // tile 2it+2 staged
        __builtin_amdgcn_s_barrier();                        // all waves: buf0 ready
        __builtin_amdgcn_sched_barrier(0);
        LOADF(aX, bX, 0);
        __builtin_amdgcn_s_setprio(1);
        MME(aY, bY);
        __builtin_amdgcn_s_setprio(0);
    }

    asm volatile("s_waitcnt vmcnt(0) lgkmcnt(0)" ::: "memory");  // drain trailing ops

    // epilogue: row = m0 + wm*64 + mi*16 + (lane>>4)*4 + r ; col = n0 + wn*64 + nj*16 + am
    const int rq = (lane >> 4) << 2;
    const int er = m0 + wm * 64;
    const int ec = n0 + wn * 64 + am;
#pragma unroll
    for (int mi = 0; mi < 4; ++mi) {
#pragma unroll
        for (int nj = 0; nj < 4; ++nj) {
            int col = ec + nj * 16;
#pragma unroll
            for (int r = 0; r < 4; ++r) {
                int row = er + mi * 16 + rq + r;
                float v = acc[mi][nj][r];
                if (MODE == 0) {
                    out_bf[(size_t)row * DI + col] = f2b(v);
                } else if (MODE == 1) {
                    v += bias[col];
                    out_bf[(size_t)row * DI + col] = f2b(v);
                } else if (MODE == 2) {
                    v += bias[col];
                    float s = 1.f / (1.f + __expf(-v));
                    s = fminf(fmaxf(s, 1e-4f), 1.f);
                    out_bf[(size_t)row * DI + col] = f2b(s);
                } else { // MODE 4: Mbig[o][z*1024 + cm]
                    out_bf[(size_t)row * 4096 + (size_t)blockIdx.z * 1024 + col] = f2b(v);
                }
            }
        }
    }
}

// ---------------- B/C projection: MFMA split-K ----------------
__global__ void __launch_bounds__(256)
bc_mfma(const unsigned short* __restrict__ u,
        const unsigned short* __restrict__ w,
        float* __restrict__ pc)
{
    const int t = threadIdx.x;
    const int lane = t & 63;
    const int wave = t >> 6;
    const int ks = blockIdx.x;                    // 0..BCKS-1
    const int m0 = blockIdx.y * 128 + wave * 32;
    const int am = lane & 15, quad = lane >> 4;

    f32x4 acc[2][2];
#pragma unroll
    for (int i = 0; i < 2; ++i)
#pragma unroll
        for (int j = 0; j < 2; ++j)
            acc[i][j] = f32x4{0.f, 0.f, 0.f, 0.f};

    const int kbase = ks * (DI / BCKS);
    const unsigned short* ur0 = u + (size_t)(m0 + am) * DI;
    const unsigned short* ur1 = u + (size_t)(m0 + 16 + am) * DI;
    const unsigned short* wr0 = w + (size_t)am * DI;
    const unsigned short* wr1 = w + (size_t)(16 + am) * DI;
#pragma unroll 2
    for (int kk = 0; kk < DI / BCKS; kk += 32) {
        int k = kbase + kk + quad * 8;
        bf16x8 a0 = *(const bf16x8*)(ur0 + k);
        bf16x8 a1 = *(const bf16x8*)(ur1 + k);
        bf16x8 b0 = *(const bf16x8*)(wr0 + k);
        bf16x8 b1 = *(const bf16x8*)(wr1 + k);
        acc[0][0] = __builtin_amdgcn_mfma_f32_16x16x32_bf16(a0, b0, acc[0][0], 0, 0, 0);
        acc[0][1] = __builtin_amdgcn_mfma_f32_16x16x32_bf16(a0, b1, acc[0][1], 0, 0, 0);
        acc[1][0] = __builtin_amdgcn_mfma_f32_16x16x32_bf16(a1, b0, acc[1][0], 0, 0, 0);
        acc[1][1] = __builtin_amdgcn_mfma_f32_16x16x32_bf16(a1, b1, acc[1][1], 0, 0, 0);
    }
    float* base = pc + (size_t)ks * MTOT * 32;
#pragma unroll
    for (int i = 0; i < 2; ++i)
#pragma unroll
        for (int j = 0; j < 2; ++j)
#pragma unroll
            for (int r = 0; r < 4; ++r) {
                int row = m0 + i * 16 + quad * 4 + r;
                int col = j * 16 + am;
                base[(size_t)row * 32 + col] = acc[i][j][r];
            }
}

__global__ void __launch_bounds__(256)
bc_reduce(const float* __restrict__ pc, float* __restrict__ outf)
{
    int i = blockIdx.x * 256 + threadIdx.x;       // float4 index, 32768 total
    const float4* p4 = (const float4*)pc;
    float4 s = p4[i];
#pragma unroll
    for (int ks = 1; ks < BCKS; ++ks) {
        float4 v = p4[(size_t)ks * (MTOT * 8) + i];
        s.x += v.x; s.y += v.y; s.z += v.z; s.w += v.w;
    }
    ((float4*)outf)[i] = s;
}

// ---------------- chunked selective scan ----------------
__global__ void __launch_bounds__(256)
scan_p1(const unsigned short* __restrict__ dt_bf,
        const unsigned short* __restrict__ u_bf,
        const float* __restrict__ bcf,
        const float* __restrict__ A_log,
        float* __restrict__ Pbuf,
        float* __restrict__ Sbuf)
{
    const int t = threadIdx.x;
    const int blk = blockIdx.x;          // 1024 = c(64) x dh(8) x b(2)
    const int c  = blk & (NC - 1);
    const int dh = (blk >> 6) & 7;
    const int b  = blk >> 9;
    const int d  = dh * 256 + t;

    float Adn[16];
    {
        const float4* ar = (const float4*)(A_log + (size_t)d * DSN);
#pragma unroll
        for (int q = 0; q < 4; ++q) {
            float4 v = ar[q];
            Adn[q * 4 + 0] = -__expf(v.x);
            Adn[q * 4 + 1] = -__expf(v.y);
            Adn[q * 4 + 2] = -__expf(v.z);
            Adn[q * 4 + 3] = -__expf(v.w);
        }
    }
    float s[16], P[16];
#pragma unroll
    for (int n = 0; n < 16; ++n) { s[n] = 0.f; P[n] = 1.f; }

    const size_t rowbase = (size_t)b * SEQL + (size_t)c * CL;
    for (int l0 = 0; l0 < CL; l0 += 4) {
        float dt4[4], u4[4];
#pragma unroll
        for (int j = 0; j < 4; ++j) {
            size_t rb = rowbase + l0 + j;
            dt4[j] = b2f(dt_bf[rb * DI + d]);
            u4[j] = b2f(u_bf[rb * DI + d]);
        }
#pragma unroll
        for (int j = 0; j < 4; ++j) {
            size_t rb = rowbase + l0 + j;
            const float4* Br = (const float4*)(bcf + rb * 32);
            float Bn[16];
#pragma unroll
            for (int q = 0; q < 4; ++q) {
                float4 v = Br[q];
                Bn[q * 4 + 0] = v.x; Bn[q * 4 + 1] = v.y;
                Bn[q * 4 + 2] = v.z; Bn[q * 4 + 3] = v.w;
            }
            float dt = dt4[j];
            float dBu = dt * u4[j];
#pragma unroll
            for (int n = 0; n < 16; ++n) {
                float x = dt * Adn[n];
                x = fminf(fmaxf(x, -5.f), 5.f);
                float dA = __expf(x);
                P[n] *= dA;
                s[n] = dA * s[n] + (dBu * Bn[n] + 1e-6f);
            }
        }
    }
    size_t ob = (((size_t)c * BATCHN + b) * DI + d) * DSN;
#pragma unroll
    for (int q = 0; q < 4; ++q) {
        ((float4*)(Pbuf + ob))[q] = make_float4(P[q*4], P[q*4+1], P[q*4+2], P[q*4+3]);
        ((float4*)(Sbuf + ob))[q] = make_float4(s[q*4], s[q*4+1], s[q*4+2], s[q*4+3]);
    }
}

__global__ void __launch_bounds__(256)
scan_p2(const float* __restrict__ Pbuf,
        const float* __restrict__ Sbuf,
        float* __restrict__ Ibuf)
{
    const int i = blockIdx.x * 256 + threadIdx.x;  // (b*DI+d)*16+n, 65536
    const int stride = BATCHN * DI * DSN;          // 65536
    float s = 0.f;
    for (int c0 = 0; c0 < NC; c0 += 8) {
        float Pv[8], Sv[8];
#pragma unroll
        for (int j = 0; j < 8; ++j) {
            size_t idx = (size_t)(c0 + j) * stride + i;
            Pv[j] = Pbuf[idx];
            Sv[j] = Sbuf[idx];
        }
#pragma unroll
        for (int j = 0; j < 8; ++j) {
            size_t idx = (size_t)(c0 + j) * stride + i;
            Ibuf[idx] = s;
            s = Pv[j] * s + Sv[j];
        }
    }
}

__global__ void __launch_bounds__(256)
scan_p3(const unsigned short* __restrict__ dt_bf,
        const unsigned short* __restrict__ u_bf,
        const float* __restrict__ bcf,
        const unsigned short* __restrict__ z_bf,
        const float* __restrict__ A_log,
        const float* __restrict__ Dvec,
        const float* __restrict__ Ibuf,
        unsigned short* __restrict__ y_bf)
{
    const int t = threadIdx.x;
    const int blk = blockIdx.x;
    const int c  = blk & (NC - 1);
    const int dh = (blk >> 6) & 7;
    const int b  = blk >> 9;
    const int d  = dh * 256 + t;

    float Adn[16];
    {
        const float4* ar = (const float4*)(A_log + (size_t)d * DSN);
#pragma unroll
        for (int q = 0; q < 4; ++q) {
            float4 v = ar[q];
            Adn[q * 4 + 0] = -__expf(v.x);
            Adn[q * 4 + 1] = -__expf(v.y);
            Adn[q * 4 + 2] = -__expf(v.z);
            Adn[q * 4 + 3] = -__expf(v.w);
        }
    }
    const float Dd = Dvec[d];
    float s[16];
    {
        size_t ib = (((size_t)c * BATCHN + b) * DI + d) * DSN;
#pragma unroll
        for (int q = 0; q < 4; ++q) {
            float4 v = ((const float4*)(Ibuf + ib))[q];
            s[q * 4 + 0] = v.x; s[q * 4 + 1] = v.y;
            s[q * 4 + 2] = v.z; s[q * 4 + 3] = v.w;
        }
    }

    const size_t rowbase = (size_t)b * SEQL + (size_t)c * CL;
    for (int l0 = 0; l0 < CL; l0 += 4) {
        float dt4[4], u4[4], z4[4];
#pragma unroll
        for (int j = 0; j < 4; ++j) {
            size_t rb = rowbase + l0 + j;
            dt4[j] = b2f(dt_bf[rb * DI + d]);
            u4[j] = b2f(u_bf[rb * DI + d]);
            z4[j] = b2f(z_bf[rb * DI + d]);
        }
#pragma unroll
        for (int j = 0; j < 4; ++j) {
            size_t rb = rowbase + l0 + j;
            const float4* Br = (const float4*)(bcf + rb * 32);
            float Bn[16], Cn[16];
#pragma unroll
            for (int q = 0; q < 4; ++q) {
                float4 v = Br[q];
                Bn[q * 4 + 0] = v.x; Bn[q * 4 + 1] = v.y;
                Bn[q * 4 + 2] = v.z; Bn[q * 4 + 3] = v.w;
                float4 w = Br[q + 4];
                Cn[q * 4 + 0] = w.x; Cn[q * 4 + 1] = w.y;
                Cn[q * 4 + 2] = w.z; Cn[q * 4 + 3] = w.w;
            }
            float dt = dt4[j];
            float dBu = dt * u4[j];
            float y = 0.f;
#pragma unroll
            for (int n = 0; n < 16; ++n) {
                float x = dt * Adn[n];
                x = fminf(fmaxf(x, -5.f), 5.f);
                float dA = __expf(x);
                s[n] = dA * s[n] + (dBu * Bn[n] + 1e-6f);
                y += s[n] * Cn[n];
            }
            y += Dd * u4[j];
            float zz = z4[j];
            y *= zz / (1.f + __expf(-zz));
            y_bf[rb * DI + d] = f2b(y);
        }
    }
}

// ---------------- launch ----------------
extern "C" void kernel_launch(void* const* d_in, const int* in_sizes, int n_in,
                              void* d_out, int out_size, void* d_ws, size_t ws_size,
                              hipStream_t stream) {
    const float* x     = (const float*)d_in[0];
    const float* ipw   = (const float*)d_in[1];
    const float* convw = (const float*)d_in[2];
    const float* convb = (const float*)d_in[3];
    const float* dtw   = (const float*)d_in[4];
    const float* dtb   = (const float*)d_in[5];
    const float* alog  = (const float*)d_in[6];
    const float* dvec  = (const float*)d_in[7];
    const float* bw    = (const float*)d_in[8];
    const float* cwm   = (const float*)d_in[9];
    const float* ow    = (const float*)d_in[10];
    float* out = (float*)d_out;

    char* ws = (char*)d_ws;
    size_t off = 0;
    auto carve = [&](size_t bytes) {
        char* p = ws + off;
        off += (bytes + 255) & ~(size_t)255;
        return p;
    };
    unsigned short* xpad   = (unsigned short*)carve((size_t)BATCHN * PADL * DM * 2);
    unsigned short* ipz_bf = (unsigned short*)carve((size_t)DI * DM * 2);
    unsigned short* Pt_bf  = (unsigned short*)carve((size_t)DM * DI * 2);
    unsigned short* wk_bf  = (unsigned short*)carve((size_t)4 * DI * DI * 2);
    unsigned short* mk_bf  = (unsigned short*)carve((size_t)4 * DI * DM * 2);  // Mbig [2048][4096]
    unsigned short* dtw_bf = (unsigned short*)carve((size_t)DI * DI * 2);
    unsigned short* ow_bf  = (unsigned short*)carve((size_t)DM * DI * 2);
    unsigned short* bc_bf  = (unsigned short*)carve((size_t)2 * DSN * DI * 2);
    unsigned short* z_bf   = (unsigned short*)carve((size_t)MTOT * DI * 2);
    unsigned short* u_bf   = (unsigned short*)carve((size_t)MTOT * DI * 2);
    unsigned short* dt_bf  = (unsigned short*)carve((size_t)MTOT * DI * 2);
    float*          bc_f   = (float*)carve((size_t)MTOT * 2 * DSN * 4);
    unsigned short* y_bf   = (unsigned short*)carve((size_t)MTOT * DI * 2);
    float*          Pbuf   = (float*)carve((size_t)NC * BATCHN * DI * DSN * 4);
    float*          Sbuf   = (float*)carve((size_t)NC * BATCHN * DI * DSN * 4);
    float*          Ibuf   = (float*)carve((size_t)NC * BATCHN * DI * DSN * 4);
    float*          pc_f   = (float*)carve((size_t)BCKS * MTOT * 32 * 4);

    // converts (2 kernels)
    cvt_x_all<<<NB_XCVT + (BATCHN * 3 * DM + 255) / 256, 256, 0, stream>>>(x, xpad);
    {
        int nb = NB_CONVW + NB_TP + NB_IPZ + NB_DTW + NB_OW + 2 * NB_BW;
        cvt_w_all<<<nb, 256, 0, stream>>>(convw, ipw, dtw, ow, bw, cwm,
                                          wk_bf, Pt_bf, ipz_bf, dtw_bf, ow_bf, bc_bf);
    }

    // mk-fuse: Mbig[o][z*1024+cm] = (W_z @ P)[o][cm]
    gemm8<4><<<dim3(8, 8, 4), 512, 0, stream>>>(wk_bf, Pt_bf, nullptr, mk_bf, nullptr);
    // z-proj: z = x @ ipz^T
    gemm8<0><<<dim3(16, 16), 512, 0, stream>>>(xpad, ipz_bf, nullptr, z_bf, nullptr);
    // conv (fused, single K=4096 GEMM over xpad sliding window x Mbig^T)
    gemm8<1><<<dim3(16, 16), 512, 0, stream>>>(xpad, mk_bf, convb, u_bf, nullptr);
    // B/C projection: MFMA split-K + reduce
    bc_mfma<<<dim3(BCKS, MTOT / 128), 256, 0, stream>>>(u_bf, bc_bf, pc_f);
    bc_reduce<<<MTOT * 32 / 4 / 256, 256, 0, stream>>>(pc_f, bc_f);
    // dt projection + sigmoid/clip -> bf16
    gemm8<2><<<dim3(16, 16), 512, 0, stream>>>(u_bf, dtw_bf, dtb, dt_bf, nullptr);
    // chunked scan
    scan_p1<<<BATCHN * 8 * NC, 256, 0, stream>>>(dt_bf, u_bf, bc_f, alog, Pbuf, Sbuf);
    scan_p2<<<BATCHN * DI * DSN / 256, 256, 0, stream>>>(Pbuf, Sbuf, Ibuf);
    scan_p3<<<BATCHN * 8 * NC, 256, 0, stream>>>(dt_bf, u_bf, bc_f, z_bf, alog, dvec, Ibuf, y_bf);
    // out projection (kept on 128^2 kernel: 256 blocks at that tile)
    gemm_bt<3><<<dim3(8, 32), 256, 0, stream>>>(y_bf, ow_bf, nullptr, nullptr, out, DI);
}

// Round 4
// 463.683 us; speedup vs baseline: 1.0312x; 1.0057x over previous
//
#include <hip/hip_runtime.h>

#define BATCHN 2
#define SEQL   2048
#define DM     1024
#define DI     2048
#define DSN    16
#define MTOT   (BATCHN * SEQL)   // 4096
#define PADL   (SEQL + 3)        // 2051
#define NC     64                // scan chunks
#define CL     (SEQL / NC)       // 32
#define BCKS   8                 // bc split-K factor

typedef __attribute__((ext_vector_type(8))) __bf16 bf16x8;
typedef __attribute__((ext_vector_type(4))) float f32x4;

__device__ __forceinline__ unsigned short f2b(float f) {
    union { float f; unsigned u; } v; v.f = f;
    unsigned r = v.u + 0x7FFF + ((v.u >> 16) & 1);
    return (unsigned short)(r >> 16);
}
__device__ __forceinline__ float b2f(unsigned short b) {
    union { float f; unsigned u; } v; v.u = ((unsigned)b) << 16;
    return v.f;
}

__device__ __forceinline__ void gl_lds16(const void* g, void* l) {
    __builtin_amdgcn_global_load_lds(
        (const __attribute__((address_space(1))) unsigned int*)g,
        (__attribute__((address_space(3))) unsigned int*)l, 16, 0, 0);
}

// XCD-aware block swizzle: 8 XCDs arranged 2 (x) x 4 (y) over the tile grid;
// each XCD covers a contiguous rectangle. Requires gx%2==0, gy%4==0.
__device__ __forceinline__ void swz(int& bx, int& by) {
    int gx = gridDim.x, gy = gridDim.y;
    int lin = blockIdx.y * gx + blockIdx.x;
    int xcd = lin & 7, k = lin >> 3;
    int rw = gx >> 1, rh = gy >> 2;
    by = (xcd >> 1) * rh + k / rw;
    bx = (xcd & 1) * rw + k % rw;
}

// ---------------- single merged convert kernel ----------------
// Regions (by blockIdx.x):
//   CW4:  convw fp32 [DI][DI][4] -> 4 bf16 planes wk[k][DI][DI], ushort4 writes
//         (R3 bug: store index was the pair index i, not i/4 -> 4x stride. Fixed.)
//   TP:   ipw xc-half transpose -> Pt [DM][DI]
//   IPZ/DTW/OW/BW/CW: straight fp32->bf16 float4 converts
//   XCVT: x fp32 -> xpad bf16 (+3-row lead pad), XZERO: zero lead rows
#define NB_CW4  (DI * DI / 4 / 256)        // 4096
#define NB_TP   ((DM / 32) * (DI / 32))    // 2048
#define NB_IPZ  (DI * DM / 4 / 256)        // 2048
#define NB_DTW  (DI * DI / 4 / 256)        // 4096
#define NB_OW   (DM * DI / 4 / 256)        // 2048
#define NB_BW   (DSN * DI / 4 / 256 + 1)   // 33
#define NB_XCVT (MTOT * DM / 4 / 256)      // 4096
#define NB_XZ   ((BATCHN * 3 * DM + 255) / 256)  // 24
#define NB_CVT_ALL (NB_CW4 + NB_TP + NB_IPZ + NB_DTW + NB_OW + 2 * NB_BW + NB_XCVT + NB_XZ)

__global__ void __launch_bounds__(256)
cvt_all(const float* __restrict__ x, const float* __restrict__ convw,
        const float* __restrict__ ipw, const float* __restrict__ dtw,
        const float* __restrict__ ow, const float* __restrict__ bw,
        const float* __restrict__ cw,
        unsigned short* __restrict__ xpad, unsigned short* __restrict__ wk,
        unsigned short* __restrict__ Pt, unsigned short* __restrict__ ipz,
        unsigned short* __restrict__ dtwb, unsigned short* __restrict__ owb,
        unsigned short* __restrict__ bcb)
{
    __shared__ float tile[32][33];
    int blk = blockIdx.x;
    int t = threadIdx.x;
    if (blk < NB_CW4) {
        // 4 consecutive (o,c) float4-groups per thread -> one ushort4 per plane
        int g = blk * 256 + t;                // ushort4 slot in each plane
        int i = g * 4;                        // float4 index into convw (= pair idx)
        const float4* cw4 = (const float4*)convw;
        float4 v0 = cw4[i + 0], v1 = cw4[i + 1], v2 = cw4[i + 2], v3 = cw4[i + 3];
#pragma unroll
        for (int k = 0; k < 4; ++k) {
            float e0 = (&v0.x)[k], e1 = (&v1.x)[k], e2 = (&v2.x)[k], e3 = (&v3.x)[k];
            ushort4 o;
            o.x = f2b(e0); o.y = f2b(e1); o.z = f2b(e2); o.w = f2b(e3);
            ((ushort4*)(wk + (size_t)k * DI * DI))[g] = o;
        }
        return;
    }
    blk -= NB_CW4;
    if (blk < NB_TP) {
        int ct = (blk & 31) * 32, it = (blk >> 5) * 32;
        int tx = t & 31, ty = t >> 5;   // 32 x 8
#pragma unroll
        for (int r = 0; r < 4; ++r)
            tile[ty + r * 8][tx] = ipw[(size_t)(it + ty + r * 8) * DM + ct + tx];
        __syncthreads();
#pragma unroll
        for (int r = 0; r < 4; ++r)
            Pt[(size_t)(ct + ty + r * 8) * DI + it + tx] = f2b(tile[tx][ty + r * 8]);
        return;
    }
    blk -= NB_TP;
    if (blk < NB_IPZ + NB_DTW + NB_OW + 2 * NB_BW) {
        const float* src;
        unsigned short* dst;
        int n4;
        if (blk < NB_IPZ) {
            src = ipw + (size_t)DI * DM; dst = ipz; n4 = DI * DM / 4;
        } else if ((blk -= NB_IPZ) < NB_DTW) {
            src = dtw; dst = dtwb; n4 = DI * DI / 4;
        } else if ((blk -= NB_DTW) < NB_OW) {
            src = ow; dst = owb; n4 = DM * DI / 4;
        } else if ((blk -= NB_OW) < NB_BW) {
            src = bw; dst = bcb; n4 = DSN * DI / 4;
        } else {
            blk -= NB_BW;
            src = cw; dst = bcb + (size_t)DSN * DI; n4 = DSN * DI / 4;
        }
        int i = blk * 256 + t;
        if (i < n4) {
            float4 v = ((const float4*)src)[i];
            ushort4 o;
            o.x = f2b(v.x); o.y = f2b(v.y); o.z = f2b(v.z); o.w = f2b(v.w);
            ((ushort4*)dst)[i] = o;
        }
        return;
    }
    blk -= NB_IPZ + NB_DTW + NB_OW + 2 * NB_BW;
    if (blk < NB_XCVT) {
        int i = blk * 256 + t;
        int b = i >> 19;
        float4 v = ((const float4*)x)[i];
        ushort4 o;
        o.x = f2b(v.x); o.y = f2b(v.y); o.z = f2b(v.z); o.w = f2b(v.w);
        ((ushort4*)xpad)[i + (b + 1) * (3 * DM / 4)] = o;
        return;
    }
    blk -= NB_XCVT;
    {
        int i = blk * 256 + t;
        if (i < BATCHN * 3 * DM) {
            int b = i / (3 * DM);
            int r = i % (3 * DM);
            xpad[(size_t)b * PADL * DM + r] = 0;
        }
    }
}

// ---------------- legacy 128x128 MFMA GEMM (kept for MODE 3 = out-proj) ----
template<int MODE>
__global__ void __launch_bounds__(256)
gemm_bt(const unsigned short* __restrict__ Abase,
        const unsigned short* __restrict__ Bbase,
        const float* __restrict__ bias,
        unsigned short* __restrict__ out_bf,
        float* __restrict__ out_f,
        int K)
{
    __shared__ __align__(16) unsigned short As[128 * 64];
    __shared__ __align__(16) unsigned short Bs[128 * 64];

    const int t = threadIdx.x;
    const int lane = t & 63;
    const int wave = t >> 6;
    const int wm = wave & 1, wn = wave >> 1;
    int bx, by;
    swz(bx, by);
    const int m0 = by * 128, n0 = bx * 128;
    const int srow = t >> 3;                          // 0..31
    const int scol = (t & 7) * 8;                     // LDS physical col (bf16)
    const int gcol = (((t & 7) ^ (srow & 7))) * 8;    // swizzled global col

    f32x4 acc[4][4];
#pragma unroll
    for (int i = 0; i < 4; ++i)
#pragma unroll
        for (int j = 0; j < 4; ++j)
            acc[i][j] = f32x4{0.f, 0.f, 0.f, 0.f};

    const unsigned short* arow[4];
    const unsigned short* brow[4];
#pragma unroll
    for (int i = 0; i < 4; ++i) {
        int rg = m0 + srow + i * 32;
        arow[i] = Abase + (size_t)rg * K;
        int ng = n0 + srow + i * 32;
        brow[i] = Bbase + (size_t)ng * K;
    }
    for (int k0 = 0; k0 < K; k0 += 64) {
#pragma unroll
        for (int i = 0; i < 4; ++i)
            gl_lds16(arow[i] + k0 + gcol, &As[(size_t)(srow + i * 32) * 64 + scol]);
#pragma unroll
        for (int i = 0; i < 4; ++i)
            gl_lds16(brow[i] + k0 + gcol, &Bs[(size_t)(srow + i * 32) * 64 + scol]);
        __syncthreads();
        const int qa = (lane >> 4) * 8;
        const int am = lane & 15;
        const int sw = (am & 7) << 3;   // XOR swizzle on element col
#pragma unroll
        for (int kk = 0; kk < 64; kk += 32) {
            bf16x8 af[4], bfv[4];
#pragma unroll
            for (int i = 0; i < 4; ++i)
                af[i] = *(const bf16x8*)&As[(wm * 64 + i * 16 + am) * 64 + ((kk + qa) ^ sw)];
#pragma unroll
            for (int j = 0; j < 4; ++j)
                bfv[j] = *(const bf16x8*)&Bs[(wn * 64 + j * 16 + am) * 64 + ((kk + qa) ^ sw)];
#pragma unroll
            for (int i = 0; i < 4; ++i)
#pragma unroll
                for (int j = 0; j < 4; ++j)
                    acc[i][j] = __builtin_amdgcn_mfma_f32_16x16x32_bf16(
                        af[i], bfv[j], acc[i][j], 0, 0, 0);
        }
        __syncthreads();
    }

    const int erow0 = m0 + wm * 64;
    const int ecol0 = n0 + wn * 64 + (lane & 15);
    const int rq = (lane >> 4) * 4;
#pragma unroll
    for (int i = 0; i < 4; ++i) {
#pragma unroll
        for (int j = 0; j < 4; ++j) {
            int col = ecol0 + j * 16;
#pragma unroll
            for (int r = 0; r < 4; ++r) {
                int row = erow0 + i * 16 + rq + r;
                float v = acc[i][j][r];
                if (MODE == 3) {
                    out_f[(size_t)row * DM + col] = v;
                } else {
                    out_bf[(size_t)row * DI + col] = f2b(v);
                }
            }
        }
    }
}

// ---------------- pipelined MFMA GEMM (256x128 tile, 8 waves) -------------
// R2 structure (control; ~946 TF structural ceiling for 64x64/wave geometry).
#define STAGE(buf, kt) do { \
    const int kc_ = ((kt) & NTM) << 6; \
    gl_lds16(pA + 0 * 64 * SA + kc_, &lds[(buf) * 16384 + ldsA + 0 * 4096]); \
    gl_lds16(pA + 1 * 64 * SA + kc_, &lds[(buf) * 16384 + ldsA + 1 * 4096]); \
    gl_lds16(pA + 2 * 64 * SA + kc_, &lds[(buf) * 16384 + ldsA + 2 * 4096]); \
    gl_lds16(pA + 3 * 64 * SA + kc_, &lds[(buf) * 16384 + ldsA + 3 * 4096]); \
    gl_lds16(pB + 0 * 64 * SB + kc_, &lds[32768 + (buf) * 8192 + ldsB + 0 * 4096]); \
    gl_lds16(pB + 1 * 64 * SB + kc_, &lds[32768 + (buf) * 8192 + ldsB + 1 * 4096]); \
} while (0)

#define LOADF(AF, BF, buf) do { \
    const unsigned short* _ab = &lds[(buf) * 16384 + arow]; \
    const unsigned short* _bb = &lds[32768 + (buf) * 8192 + brow]; \
    _Pragma("unroll") \
    for (int _i = 0; _i < 4; ++_i) { \
        AF[_i][0] = *(const bf16x8*)&_ab[_i * 1024 + c0]; \
        AF[_i][1] = *(const bf16x8*)&_ab[_i * 1024 + c1]; \
    } \
    _Pragma("unroll") \
    for (int _j = 0; _j < 4; ++_j) { \
        BF[_j][0] = *(const bf16x8*)&_bb[_j * 1024 + c0]; \
        BF[_j][1] = *(const bf16x8*)&_bb[_j * 1024 + c1]; \
    } \
} while (0)

#define MME(AF, BF) do { \
    _Pragma("unroll") \
    for (int _i = 0; _i < 4; ++_i) \
    _Pragma("unroll") \
    for (int _j = 0; _j < 4; ++_j) { \
        acc[_i][_j] = __builtin_amdgcn_mfma_f32_16x16x32_bf16(AF[_i][0], BF[_j][0], acc[_i][_j], 0, 0, 0); \
        acc[_i][_j] = __builtin_amdgcn_mfma_f32_16x16x32_bf16(AF[_i][1], BF[_j][1], acc[_i][_j], 0, 0, 0); \
    } \
} while (0)

template<int MODE>
__global__ void __launch_bounds__(512, 1)
gemm8(const unsigned short* __restrict__ Abase,
      const unsigned short* __restrict__ Bbase,
      const float* __restrict__ bias,
      unsigned short* __restrict__ out_bf,
      float* __restrict__ out_f)
{
    constexpr int K   = (MODE == 0) ? 1024 : (MODE == 1) ? 4096 : 2048;
    constexpr int SA  = (MODE == 2 || MODE == 4) ? 2048 : 1024;
    constexpr int SB  = (MODE == 0) ? 1024 : (MODE == 1) ? 4096 : 2048;
    constexpr int NT  = K / 64;
    constexpr int NTM = NT - 1;
    constexpr int NI  = NT / 2;
    (void)out_f;

    __shared__ __align__(16) unsigned short lds[49152];   // 96 KiB

    const int t = threadIdx.x;
    const int lane = t & 63;
    const int wave = t >> 6;       // 0..7
    const int wm = wave >> 1;      // 0..3 (M quarters, 64 rows each)
    const int wn = wave & 1;       // 0..1 (N halves, 64 cols each)
    int bx, by;
    swz(bx, by);
    const int m0 = by * 256, n0 = bx * 128;

    const unsigned short* Ap;
    if (MODE == 0)      Ap = Abase + ((size_t)(m0 >> 11) * PADL + 3 + (m0 & 2047)) * DM;
    else if (MODE == 1) Ap = Abase + ((size_t)(m0 >> 11) * PADL + (m0 & 2047)) * DM;
    else if (MODE == 4) Ap = Abase + (size_t)blockIdx.z * DI * DI + (size_t)m0 * SA;
    else                Ap = Abase + (size_t)m0 * SA;
    const unsigned short* Bp = Bbase + (size_t)n0 * SB;

    const int strow = t >> 3;                           // 0..63
    const int gcs = ((t & 7) ^ (strow & 7)) * 8;        // inverse-swizzled src col
    const unsigned short* pA = Ap + (size_t)strow * SA + gcs;
    const unsigned short* pB = Bp + (size_t)strow * SB + gcs;
    const int ldsA = t * 8;
    const int ldsB = t * 8;

    const int am = lane & 15;
    const int qa = (lane >> 4) << 3;
    const int sw = (am & 7) << 3;
    const int c0 = qa ^ sw;
    const int c1 = (32 + qa) ^ sw;
    const int arow = (wm * 64 + am) * 64;
    const int brow = (wn * 64 + am) * 64;

    f32x4 acc[4][4];
#pragma unroll
    for (int i = 0; i < 4; ++i)
#pragma unroll
        for (int j = 0; j < 4; ++j)
            acc[i][j] = f32x4{0.f, 0.f, 0.f, 0.f};

    bf16x8 aX[4][2], bX[4][2], aY[4][2], bY[4][2];

    STAGE(0, 0);
    STAGE(1, 1);
    asm volatile("s_waitcnt vmcnt(6)" ::: "memory");
    __builtin_amdgcn_s_barrier();
    __builtin_amdgcn_sched_barrier(0);
    LOADF(aX, bX, 0);

#pragma unroll 1
    for (int it = 0; it < NI; ++it) {
        asm volatile("s_waitcnt lgkmcnt(0)" ::: "memory");
        __builtin_amdgcn_s_barrier();
        __builtin_amdgcn_sched_barrier(0);
        STAGE(0, 2 * it + 2);
        asm volatile("s_waitcnt vmcnt(6)" ::: "memory");
        __builtin_amdgcn_s_barrier();
        __builtin_amdgcn_sched_barrier(0);
        LOADF(aY, bY, 1);
        __builtin_amdgcn_s_setprio(1);
        MME(aX, bX);
        __builtin_amdgcn_s_setprio(0);
        asm volatile("s_waitcnt lgkmcnt(0)" ::: "memory");
        __builtin_amdgcn_s_barrier();
        __builtin_amdgcn_sched_barrier(0);
        STAGE(1, 2 * it + 3);
        asm volatile("s_waitcnt vmcnt(6)" ::: "memory");
        __builtin_amdgcn_s_barrier();
        __builtin_amdgcn_sched_barrier(0);
        LOADF(aX, bX, 0);
        __builtin_amdgcn_s_setprio(1);
        MME(aY, bY);
        __builtin_amdgcn_s_setprio(0);
    }

    asm volatile("s_waitcnt vmcnt(0) lgkmcnt(0)" ::: "memory");

    const int rq = (lane >> 4) << 2;
    const int er = m0 + wm * 64;
    const int ec = n0 + wn * 64 + am;
#pragma unroll
    for (int mi = 0; mi < 4; ++mi) {
#pragma unroll
        for (int nj = 0; nj < 4; ++nj) {
            int col = ec + nj * 16;
#pragma unroll
            for (int r = 0; r < 4; ++r) {
                int row = er + mi * 16 + rq + r;
                float v = acc[mi][nj][r];
                if (MODE == 0) {
                    out_bf[(size_t)row * DI + col] = f2b(v);
                } else if (MODE == 1) {
                    v += bias[col];
                    out_bf[(size_t)row * DI + col] = f2b(v);
                } else if (MODE == 2) {
                    v += bias[col];
                    float s = 1.f / (1.f + __expf(-v));
                    s = fminf(fmaxf(s, 1e-4f), 1.f);
                    out_bf[(size_t)row * DI + col] = f2b(s);
                } else { // MODE 4: Mbig[o][z*1024 + cm]
                    out_bf[(size_t)row * 4096 + (size_t)blockIdx.z * 1024 + col] = f2b(v);
                }
            }
        }
    }
}

// ---------------- B/C projection: MFMA split-K ----------------
__global__ void __launch_bounds__(256)
bc_mfma(const unsigned short* __restrict__ u,
        const unsigned short* __restrict__ w,
        float* __restrict__ pc)
{
    const int t = threadIdx.x;
    const int lane = t & 63;
    const int wave = t >> 6;
    const int ks = blockIdx.x;                    // 0..BCKS-1
    const int m0 = blockIdx.y * 128 + wave * 32;
    const int am = lane & 15, quad = lane >> 4;

    f32x4 acc[2][2];
#pragma unroll
    for (int i = 0; i < 2; ++i)
#pragma unroll
        for (int j = 0; j < 2; ++j)
            acc[i][j] = f32x4{0.f, 0.f, 0.f, 0.f};

    const int kbase = ks * (DI / BCKS);
    const unsigned short* ur0 = u + (size_t)(m0 + am) * DI;
    const unsigned short* ur1 = u + (size_t)(m0 + 16 + am) * DI;
    const unsigned short* wr0 = w + (size_t)am * DI;
    const unsigned short* wr1 = w + (size_t)(16 + am) * DI;
#pragma unroll 2
    for (int kk = 0; kk < DI / BCKS; kk += 32) {
        int k = kbase + kk + quad * 8;
        bf16x8 a0 = *(const bf16x8*)(ur0 + k);
        bf16x8 a1 = *(const bf16x8*)(ur1 + k);
        bf16x8 b0 = *(const bf16x8*)(wr0 + k);
        bf16x8 b1 = *(const bf16x8*)(wr1 + k);
        acc[0][0] = __builtin_amdgcn_mfma_f32_16x16x32_bf16(a0, b0, acc[0][0], 0, 0, 0);
        acc[0][1] = __builtin_amdgcn_mfma_f32_16x16x32_bf16(a0, b1, acc[0][1], 0, 0, 0);
        acc[1][0] = __builtin_amdgcn_mfma_f32_16x16x32_bf16(a1, b0, acc[1][0], 0, 0, 0);
        acc[1][1] = __builtin_amdgcn_mfma_f32_16x16x32_bf16(a1, b1, acc[1][1], 0, 0, 0);
    }
    float* base = pc + (size_t)ks * MTOT * 32;
#pragma unroll
    for (int i = 0; i < 2; ++i)
#pragma unroll
        for (int j = 0; j < 2; ++j)
#pragma unroll
            for (int r = 0; r < 4; ++r) {
                int row = m0 + i * 16 + quad * 4 + r;
                int col = j * 16 + am;
                base[(size_t)row * 32 + col] = acc[i][j][r];
            }
}

// ---------------- chunked selective scan ----------------
// scan_p1 reduces the bc split-K partials (pc) into LDS (bitwise the same
// ks-order sum as the old bc_reduce) and, from the dh==0 blocks, publishes
// the reduced bcf for scan_p3.
__global__ void __launch_bounds__(256)
scan_p1(const unsigned short* __restrict__ dt_bf,
        const unsigned short* __restrict__ u_bf,
        const float* __restrict__ pc,
        const float* __restrict__ A_log,
        float* __restrict__ Pbuf,
        float* __restrict__ Sbuf,
        float* __restrict__ bcf)
{
    const int t = threadIdx.x;
    const int blk = blockIdx.x;          // 1024 = c(64) x dh(8) x b(2)
    const int c  = blk & (NC - 1);
    const int dh = (blk >> 6) & 7;
    const int b  = blk >> 9;
    const int d  = dh * 256 + t;

    const size_t rowbase = (size_t)b * SEQL + (size_t)c * CL;

    __shared__ float sm[CL][32];
    for (int idx = t; idx < CL * 32; idx += 256) {
        int r = idx >> 5, n = idx & 31;
        size_t base = (rowbase + r) * 32 + n;
        float s = pc[base];
#pragma unroll
        for (int ks = 1; ks < BCKS; ++ks)
            s += pc[(size_t)ks * (MTOT * 32) + base];
        sm[r][n] = s;
        if (dh == 0) bcf[base] = s;
    }

    float Adn[16];
    {
        const float4* ar = (const float4*)(A_log + (size_t)d * DSN);
#pragma unroll
        for (int q = 0; q < 4; ++q) {
            float4 v = ar[q];
            Adn[q * 4 + 0] = -__expf(v.x);
            Adn[q * 4 + 1] = -__expf(v.y);
            Adn[q * 4 + 2] = -__expf(v.z);
            Adn[q * 4 + 3] = -__expf(v.w);
        }
    }
    float s[16], P[16];
#pragma unroll
    for (int n = 0; n < 16; ++n) { s[n] = 0.f; P[n] = 1.f; }

    __syncthreads();

    for (int l0 = 0; l0 < CL; l0 += 4) {
        float dt4[4], u4[4];
#pragma unroll
        for (int j = 0; j < 4; ++j) {
            size_t rb = rowbase + l0 + j;
            dt4[j] = b2f(dt_bf[rb * DI + d]);
            u4[j] = b2f(u_bf[rb * DI + d]);
        }
#pragma unroll
        for (int j = 0; j < 4; ++j) {
            const float4* Br = (const float4*)(&sm[l0 + j][0]);
            float Bn[16];
#pragma unroll
            for (int q = 0; q < 4; ++q) {
                float4 v = Br[q];
                Bn[q * 4 + 0] = v.x; Bn[q * 4 + 1] = v.y;
                Bn[q * 4 + 2] = v.z; Bn[q * 4 + 3] = v.w;
            }
            float dt = dt4[j];
            float dBu = dt * u4[j];
#pragma unroll
            for (int n = 0; n < 16; ++n) {
                float x = dt * Adn[n];
                x = fminf(fmaxf(x, -5.f), 5.f);
                float dA = __expf(x);
                P[n] *= dA;
                s[n] = dA * s[n] + (dBu * Bn[n] + 1e-6f);
            }
        }
    }
    size_t ob = (((size_t)c * BATCHN + b) * DI + d) * DSN;
#pragma unroll
    for (int q = 0; q < 4; ++q) {
        ((float4*)(Pbuf + ob))[q] = make_float4(P[q*4], P[q*4+1], P[q*4+2], P[q*4+3]);
        ((float4*)(Sbuf + ob))[q] = make_float4(s[q*4], s[q*4+1], s[q*4+2], s[q*4+3]);
    }
}

__global__ void __launch_bounds__(256)
scan_p2(const float* __restrict__ Pbuf,
        const float* __restrict__ Sbuf,
        float* __restrict__ Ibuf)
{
    const int i = blockIdx.x * 256 + threadIdx.x;  // (b*DI+d)*16+n, 65536
    const int stride = BATCHN * DI * DSN;          // 65536
    float s = 0.f;
    for (int c0 = 0; c0 < NC; c0 += 8) {
        float Pv[8], Sv[8];
#pragma unroll
        for (int j = 0; j < 8; ++j) {
            size_t idx = (size_t)(c0 + j) * stride + i;
            Pv[j] = Pbuf[idx];
            Sv[j] = Sbuf[idx];
        }
#pragma unroll
        for (int j = 0; j < 8; ++j) {
            size_t idx = (size_t)(c0 + j) * stride + i;
            Ibuf[idx] = s;
            s = Pv[j] * s + Sv[j];
        }
    }
}

__global__ void __launch_bounds__(256)
scan_p3(const unsigned short* __restrict__ dt_bf,
        const unsigned short* __restrict__ u_bf,
        const float* __restrict__ bcf,
        const unsigned short* __restrict__ z_bf,
        const float* __restrict__ A_log,
        const float* __restrict__ Dvec,
        const float* __restrict__ Ibuf,
        unsigned short* __restrict__ y_bf)
{
    const int t = threadIdx.x;
    const int blk = blockIdx.x;
    const int c  = blk & (NC - 1);
    const int dh = (blk >> 6) & 7;
    const int b  = blk >> 9;
    const int d  = dh * 256 + t;

    float Adn[16];
    {
        const float4* ar = (const float4*)(A_log + (size_t)d * DSN);
#pragma unroll
        for (int q = 0; q < 4; ++q) {
            float4 v = ar[q];
            Adn[q * 4 + 0] = -__expf(v.x);
            Adn[q * 4 + 1] = -__expf(v.y);
            Adn[q * 4 + 2] = -__expf(v.z);
            Adn[q * 4 + 3] = -__expf(v.w);
        }
    }
    const float Dd = Dvec[d];
    float s[16];
    {
        size_t ib = (((size_t)c * BATCHN + b) * DI + d) * DSN;
#pragma unroll
        for (int q = 0; q < 4; ++q) {
            float4 v = ((const float4*)(Ibuf + ib))[q];
            s[q * 4 + 0] = v.x; s[q * 4 + 1] = v.y;
            s[q * 4 + 2] = v.z; s[q * 4 + 3] = v.w;
        }
    }

    const size_t rowbase = (size_t)b * SEQL + (size_t)c * CL;
    for (int l0 = 0; l0 < CL; l0 += 4) {
        float dt4[4], u4[4], z4[4];
#pragma unroll
        for (int j = 0; j < 4; ++j) {
            size_t rb = rowbase + l0 + j;
            dt4[j] = b2f(dt_bf[rb * DI + d]);
            u4[j] = b2f(u_bf[rb * DI + d]);
            z4[j] = b2f(z_bf[rb * DI + d]);
        }
#pragma unroll
        for (int j = 0; j < 4; ++j) {
            size_t rb = rowbase + l0 + j;
            const float4* Br = (const float4*)(bcf + rb * 32);
            float Bn[16], Cn[16];
#pragma unroll
            for (int q = 0; q < 4; ++q) {
                float4 v = Br[q];
                Bn[q * 4 + 0] = v.x; Bn[q * 4 + 1] = v.y;
                Bn[q * 4 + 2] = v.z; Bn[q * 4 + 3] = v.w;
                float4 w = Br[q + 4];
                Cn[q * 4 + 0] = w.x; Cn[q * 4 + 1] = w.y;
                Cn[q * 4 + 2] = w.z; Cn[q * 4 + 3] = w.w;
            }
            float dt = dt4[j];
            float dBu = dt * u4[j];
            float y = 0.f;
#pragma unroll
            for (int n = 0; n < 16; ++n) {
                float x = dt * Adn[n];
                x = fminf(fmaxf(x, -5.f), 5.f);
                float dA = __expf(x);
                s[n] = dA * s[n] + (dBu * Bn[n] + 1e-6f);
                y += s[n] * Cn[n];
            }
            y += Dd * u4[j];
            float zz = z4[j];
            y *= zz / (1.f + __expf(-zz));
            y_bf[rb * DI + d] = f2b(y);
        }
    }
}

// ---------------- launch ----------------
extern "C" void kernel_launch(void* const* d_in, const int* in_sizes, int n_in,
                              void* d_out, int out_size, void* d_ws, size_t ws_size,
                              hipStream_t stream) {
    const float* x     = (const float*)d_in[0];
    const float* ipw   = (const float*)d_in[1];
    const float* convw = (const float*)d_in[2];
    const float* convb = (const float*)d_in[3];
    const float* dtw   = (const float*)d_in[4];
    const float* dtb   = (const float*)d_in[5];
    const float* alog  = (const float*)d_in[6];
    const float* dvec  = (const float*)d_in[7];
    const float* bw    = (const float*)d_in[8];
    const float* cwm   = (const float*)d_in[9];
    const float* ow    = (const float*)d_in[10];
    float* out = (float*)d_out;

    char* ws = (char*)d_ws;
    size_t off = 0;
    auto carve = [&](size_t bytes) {
        char* p = ws + off;
        off += (bytes + 255) & ~(size_t)255;
        return p;
    };
    unsigned short* xpad   = (unsigned short*)carve((size_t)BATCHN * PADL * DM * 2);
    unsigned short* ipz_bf = (unsigned short*)carve((size_t)DI * DM * 2);
    unsigned short* Pt_bf  = (unsigned short*)carve((size_t)DM * DI * 2);
    unsigned short* wk_bf  = (unsigned short*)carve((size_t)4 * DI * DI * 2);
    unsigned short* mk_bf  = (unsigned short*)carve((size_t)4 * DI * DM * 2);  // Mbig [2048][4096]
    unsigned short* dtw_bf = (unsigned short*)carve((size_t)DI * DI * 2);
    unsigned short* ow_bf  = (unsigned short*)carve((size_t)DM * DI * 2);
    unsigned short* bc_bf  = (unsigned short*)carve((size_t)2 * DSN * DI * 2);
    unsigned short* z_bf   = (unsigned short*)carve((size_t)MTOT * DI * 2);
    unsigned short* u_bf   = (unsigned short*)carve((size_t)MTOT * DI * 2);
    unsigned short* dt_bf  = (unsigned short*)carve((size_t)MTOT * DI * 2);
    float*          bc_f   = (float*)carve((size_t)MTOT * 2 * DSN * 4);
    unsigned short* y_bf   = (unsigned short*)carve((size_t)MTOT * DI * 2);
    float*          Pbuf   = (float*)carve((size_t)NC * BATCHN * DI * DSN * 4);
    float*          Sbuf   = (float*)carve((size_t)NC * BATCHN * DI * DSN * 4);
    float*          Ibuf   = (float*)carve((size_t)NC * BATCHN * DI * DSN * 4);
    float*          pc_f   = (float*)carve((size_t)BCKS * MTOT * 32 * 4);

    // all converts in one launch
    cvt_all<<<NB_CVT_ALL, 256, 0, stream>>>(x, convw, ipw, dtw, ow, bw, cwm,
                                            xpad, wk_bf, Pt_bf, ipz_bf, dtw_bf,
                                            ow_bf, bc_bf);

    // mk-fuse: Mbig[o][z*1024+cm] = (W_z @ P)[o][cm]
    gemm8<4><<<dim3(8, 8, 4), 512, 0, stream>>>(wk_bf, Pt_bf, nullptr, mk_bf, nullptr);
    // z-proj: z = x @ ipz^T
    gemm8<0><<<dim3(16, 16), 512, 0, stream>>>(xpad, ipz_bf, nullptr, z_bf, nullptr);
    // conv (fused, single K=4096 GEMM over xpad sliding window x Mbig^T)
    gemm8<1><<<dim3(16, 16), 512, 0, stream>>>(xpad, mk_bf, convb, u_bf, nullptr);
    // B/C projection: MFMA split-K (reduce fused into scan_p1)
    bc_mfma<<<dim3(BCKS, MTOT / 128), 256, 0, stream>>>(u_bf, bc_bf, pc_f);
    // dt projection + sigmoid/clip -> bf16
    gemm8<2><<<dim3(16, 16), 512, 0, stream>>>(u_bf, dtw_bf, dtb, dt_bf, nullptr);
    // chunked scan (p1 also reduces pc -> bcf)
    scan_p1<<<BATCHN * 8 * NC, 256, 0, stream>>>(dt_bf, u_bf, pc_f, alog, Pbuf, Sbuf, bc_f);
    scan_p2<<<BATCHN * DI * DSN / 256, 256, 0, stream>>>(Pbuf, Sbuf, Ibuf);
    scan_p3<<<BATCHN * 8 * NC, 256, 0, stream>>>(dt_bf, u_bf, bc_f, z_bf, alog, dvec, Ibuf, y_bf);
    // out projection
    gemm_bt<3><<<dim3(8, 32), 256, 0, stream>>>(y_bf, ow_bf, nullptr, nullptr, out, DI);
}

// Round 5
// 453.754 us; speedup vs baseline: 1.0538x; 1.0219x over previous
//
#include <hip/hip_runtime.h>

#define BATCHN 2
#define SEQL   2048
#define DM     1024
#define DI     2048
#define DSN    16
#define MTOT   (BATCHN * SEQL)   // 4096
#define PADL   (SEQL + 3)        // 2051
#define NC     64                // scan chunks
#define CL     (SEQL / NC)       // 32
#define BCKS   8                 // bc split-K factor

typedef __attribute__((ext_vector_type(8))) __bf16 bf16x8;
typedef __attribute__((ext_vector_type(4))) float f32x4;

__device__ __forceinline__ unsigned short f2b(float f) {
    union { float f; unsigned u; } v; v.f = f;
    unsigned r = v.u + 0x7FFF + ((v.u >> 16) & 1);
    return (unsigned short)(r >> 16);
}
__device__ __forceinline__ float b2f(unsigned short b) {
    union { float f; unsigned u; } v; v.u = ((unsigned)b) << 16;
    return v.f;
}

__device__ __forceinline__ void gl_lds16(const void* g, void* l) {
    __builtin_amdgcn_global_load_lds(
        (const __attribute__((address_space(1))) unsigned int*)g,
        (__attribute__((address_space(3))) unsigned int*)l, 16, 0, 0);
}

// XCD-aware block swizzle: 8 XCDs arranged 2 (x) x 4 (y) over the tile grid;
// each XCD covers a contiguous rectangle. Requires gx%2==0, gy%4==0.
__device__ __forceinline__ void swz(int& bx, int& by) {
    int gx = gridDim.x, gy = gridDim.y;
    int lin = blockIdx.y * gx + blockIdx.x;
    int xcd = lin & 7, k = lin >> 3;
    int rw = gx >> 1, rh = gy >> 2;
    by = (xcd >> 1) * rh + k / rw;
    bx = (xcd & 1) * rw + k % rw;
}

// ---------------- single merged convert kernel ----------------
#define NB_CW4  (DI * DI / 4 / 256)        // 4096
#define NB_TP   ((DM / 32) * (DI / 32))    // 2048
#define NB_IPZ  (DI * DM / 4 / 256)        // 2048
#define NB_DTW  (DI * DI / 4 / 256)        // 4096
#define NB_OW   (DM * DI / 4 / 256)        // 2048
#define NB_BW   (DSN * DI / 4 / 256 + 1)   // 33
#define NB_XCVT (MTOT * DM / 4 / 256)      // 4096
#define NB_XZ   ((BATCHN * 3 * DM + 255) / 256)  // 24
#define NB_CVT_ALL (NB_CW4 + NB_TP + NB_IPZ + NB_DTW + NB_OW + 2 * NB_BW + NB_XCVT + NB_XZ)

__global__ void __launch_bounds__(256)
cvt_all(const float* __restrict__ x, const float* __restrict__ convw,
        const float* __restrict__ ipw, const float* __restrict__ dtw,
        const float* __restrict__ ow, const float* __restrict__ bw,
        const float* __restrict__ cw,
        unsigned short* __restrict__ xpad, unsigned short* __restrict__ wk,
        unsigned short* __restrict__ Pt, unsigned short* __restrict__ ipz,
        unsigned short* __restrict__ dtwb, unsigned short* __restrict__ owb,
        unsigned short* __restrict__ bcb)
{
    __shared__ float tile[32][33];
    int blk = blockIdx.x;
    int t = threadIdx.x;
    if (blk < NB_CW4) {
        // 4 consecutive (o,c) float4-groups per thread -> one ushort4 per plane
        int g = blk * 256 + t;                // ushort4 slot in each plane
        int i = g * 4;                        // float4 index into convw
        const float4* cw4 = (const float4*)convw;
        float4 v0 = cw4[i + 0], v1 = cw4[i + 1], v2 = cw4[i + 2], v3 = cw4[i + 3];
#pragma unroll
        for (int k = 0; k < 4; ++k) {
            float e0 = (&v0.x)[k], e1 = (&v1.x)[k], e2 = (&v2.x)[k], e3 = (&v3.x)[k];
            ushort4 o;
            o.x = f2b(e0); o.y = f2b(e1); o.z = f2b(e2); o.w = f2b(e3);
            ((ushort4*)(wk + (size_t)k * DI * DI))[g] = o;
        }
        return;
    }
    blk -= NB_CW4;
    if (blk < NB_TP) {
        int ct = (blk & 31) * 32, it = (blk >> 5) * 32;
        int tx = t & 31, ty = t >> 5;   // 32 x 8
#pragma unroll
        for (int r = 0; r < 4; ++r)
            tile[ty + r * 8][tx] = ipw[(size_t)(it + ty + r * 8) * DM + ct + tx];
        __syncthreads();
#pragma unroll
        for (int r = 0; r < 4; ++r)
            Pt[(size_t)(ct + ty + r * 8) * DI + it + tx] = f2b(tile[tx][ty + r * 8]);
        return;
    }
    blk -= NB_TP;
    if (blk < NB_IPZ + NB_DTW + NB_OW + 2 * NB_BW) {
        const float* src;
        unsigned short* dst;
        int n4;
        if (blk < NB_IPZ) {
            src = ipw + (size_t)DI * DM; dst = ipz; n4 = DI * DM / 4;
        } else if ((blk -= NB_IPZ) < NB_DTW) {
            src = dtw; dst = dtwb; n4 = DI * DI / 4;
        } else if ((blk -= NB_DTW) < NB_OW) {
            src = ow; dst = owb; n4 = DM * DI / 4;
        } else if ((blk -= NB_OW) < NB_BW) {
            src = bw; dst = bcb; n4 = DSN * DI / 4;
        } else {
            blk -= NB_BW;
            src = cw; dst = bcb + (size_t)DSN * DI; n4 = DSN * DI / 4;
        }
        int i = blk * 256 + t;
        if (i < n4) {
            float4 v = ((const float4*)src)[i];
            ushort4 o;
            o.x = f2b(v.x); o.y = f2b(v.y); o.z = f2b(v.z); o.w = f2b(v.w);
            ((ushort4*)dst)[i] = o;
        }
        return;
    }
    blk -= NB_IPZ + NB_DTW + NB_OW + 2 * NB_BW;
    if (blk < NB_XCVT) {
        int i = blk * 256 + t;
        int b = i >> 19;
        float4 v = ((const float4*)x)[i];
        ushort4 o;
        o.x = f2b(v.x); o.y = f2b(v.y); o.z = f2b(v.z); o.w = f2b(v.w);
        ((ushort4*)xpad)[i + (b + 1) * (3 * DM / 4)] = o;
        return;
    }
    blk -= NB_XCVT;
    {
        int i = blk * 256 + t;
        if (i < BATCHN * 3 * DM) {
            int b = i / (3 * DM);
            int r = i % (3 * DM);
            xpad[(size_t)b * PADL * DM + r] = 0;
        }
    }
}

// ---------------- legacy 128x128 MFMA GEMM (kept for MODE 3 = out-proj) ----
template<int MODE>
__global__ void __launch_bounds__(256)
gemm_bt(const unsigned short* __restrict__ Abase,
        const unsigned short* __restrict__ Bbase,
        const float* __restrict__ bias,
        unsigned short* __restrict__ out_bf,
        float* __restrict__ out_f,
        int K)
{
    __shared__ __align__(16) unsigned short As[128 * 64];
    __shared__ __align__(16) unsigned short Bs[128 * 64];

    const int t = threadIdx.x;
    const int lane = t & 63;
    const int wave = t >> 6;
    const int wm = wave & 1, wn = wave >> 1;
    int bx, by;
    swz(bx, by);
    const int m0 = by * 128, n0 = bx * 128;
    const int srow = t >> 3;                          // 0..31
    const int scol = (t & 7) * 8;                     // LDS physical col (bf16)
    const int gcol = (((t & 7) ^ (srow & 7))) * 8;    // swizzled global col

    f32x4 acc[4][4];
#pragma unroll
    for (int i = 0; i < 4; ++i)
#pragma unroll
        for (int j = 0; j < 4; ++j)
            acc[i][j] = f32x4{0.f, 0.f, 0.f, 0.f};

    const unsigned short* arow[4];
    const unsigned short* brow[4];
#pragma unroll
    for (int i = 0; i < 4; ++i) {
        int rg = m0 + srow + i * 32;
        arow[i] = Abase + (size_t)rg * K;
        int ng = n0 + srow + i * 32;
        brow[i] = Bbase + (size_t)ng * K;
    }
    for (int k0 = 0; k0 < K; k0 += 64) {
#pragma unroll
        for (int i = 0; i < 4; ++i)
            gl_lds16(arow[i] + k0 + gcol, &As[(size_t)(srow + i * 32) * 64 + scol]);
#pragma unroll
        for (int i = 0; i < 4; ++i)
            gl_lds16(brow[i] + k0 + gcol, &Bs[(size_t)(srow + i * 32) * 64 + scol]);
        __syncthreads();
        const int qa = (lane >> 4) * 8;
        const int am = lane & 15;
        const int sw = (am & 7) << 3;   // XOR swizzle on element col
#pragma unroll
        for (int kk = 0; kk < 64; kk += 32) {
            bf16x8 af[4], bfv[4];
#pragma unroll
            for (int i = 0; i < 4; ++i)
                af[i] = *(const bf16x8*)&As[(wm * 64 + i * 16 + am) * 64 + ((kk + qa) ^ sw)];
#pragma unroll
            for (int j = 0; j < 4; ++j)
                bfv[j] = *(const bf16x8*)&Bs[(wn * 64 + j * 16 + am) * 64 + ((kk + qa) ^ sw)];
#pragma unroll
            for (int i = 0; i < 4; ++i)
#pragma unroll
                for (int j = 0; j < 4; ++j)
                    acc[i][j] = __builtin_amdgcn_mfma_f32_16x16x32_bf16(
                        af[i], bfv[j], acc[i][j], 0, 0, 0);
        }
        __syncthreads();
    }

    const int erow0 = m0 + wm * 64;
    const int ecol0 = n0 + wn * 64 + (lane & 15);
    const int rq = (lane >> 4) * 4;
#pragma unroll
    for (int i = 0; i < 4; ++i) {
#pragma unroll
        for (int j = 0; j < 4; ++j) {
            int col = ecol0 + j * 16;
#pragma unroll
            for (int r = 0; r < 4; ++r) {
                int row = erow0 + i * 16 + rq + r;
                float v = acc[i][j][r];
                if (MODE == 3) {
                    out_f[(size_t)row * DM + col] = v;
                } else {
                    out_bf[(size_t)row * DI + col] = f2b(v);
                }
            }
        }
    }
}

// ---------------- pipelined MFMA GEMM (256x128 tile, 8 waves) -------------
// R2 structure (control; ~946 TF structural ceiling for 64x64/wave geometry).
#define STAGE(buf, kt) do { \
    const int kc_ = ((kt) & NTM) << 6; \
    gl_lds16(pA + 0 * 64 * SA + kc_, &lds[(buf) * 16384 + ldsA + 0 * 4096]); \
    gl_lds16(pA + 1 * 64 * SA + kc_, &lds[(buf) * 16384 + ldsA + 1 * 4096]); \
    gl_lds16(pA + 2 * 64 * SA + kc_, &lds[(buf) * 16384 + ldsA + 2 * 4096]); \
    gl_lds16(pA + 3 * 64 * SA + kc_, &lds[(buf) * 16384 + ldsA + 3 * 4096]); \
    gl_lds16(pB + 0 * 64 * SB + kc_, &lds[32768 + (buf) * 8192 + ldsB + 0 * 4096]); \
    gl_lds16(pB + 1 * 64 * SB + kc_, &lds[32768 + (buf) * 8192 + ldsB + 1 * 4096]); \
} while (0)

#define LOADF(AF, BF, buf) do { \
    const unsigned short* _ab = &lds[(buf) * 16384 + arow]; \
    const unsigned short* _bb = &lds[32768 + (buf) * 8192 + brow]; \
    _Pragma("unroll") \
    for (int _i = 0; _i < 4; ++_i) { \
        AF[_i][0] = *(const bf16x8*)&_ab[_i * 1024 + c0]; \
        AF[_i][1] = *(const bf16x8*)&_ab[_i * 1024 + c1]; \
    } \
    _Pragma("unroll") \
    for (int _j = 0; _j < 4; ++_j) { \
        BF[_j][0] = *(const bf16x8*)&_bb[_j * 1024 + c0]; \
        BF[_j][1] = *(const bf16x8*)&_bb[_j * 1024 + c1]; \
    } \
} while (0)

#define MME(AF, BF) do { \
    _Pragma("unroll") \
    for (int _i = 0; _i < 4; ++_i) \
    _Pragma("unroll") \
    for (int _j = 0; _j < 4; ++_j) { \
        acc[_i][_j] = __builtin_amdgcn_mfma_f32_16x16x32_bf16(AF[_i][0], BF[_j][0], acc[_i][_j], 0, 0, 0); \
        acc[_i][_j] = __builtin_amdgcn_mfma_f32_16x16x32_bf16(AF[_i][1], BF[_j][1], acc[_i][_j], 0, 0, 0); \
    } \
} while (0)

template<int MODE>
__global__ void __launch_bounds__(512, 1)
gemm8(const unsigned short* __restrict__ Abase,
      const unsigned short* __restrict__ Bbase,
      const float* __restrict__ bias,
      unsigned short* __restrict__ out_bf,
      float* __restrict__ out_f)
{
    constexpr int K   = (MODE == 0) ? 1024 : (MODE == 1) ? 4096 : 2048;
    constexpr int SA  = (MODE == 2 || MODE == 4) ? 2048 : 1024;
    constexpr int SB  = (MODE == 0) ? 1024 : (MODE == 1) ? 4096 : 2048;
    constexpr int NT  = K / 64;
    constexpr int NTM = NT - 1;
    constexpr int NI  = NT / 2;
    (void)out_f;

    __shared__ __align__(16) unsigned short lds[49152];   // 96 KiB

    const int t = threadIdx.x;
    const int lane = t & 63;
    const int wave = t >> 6;       // 0..7
    const int wm = wave >> 1;      // 0..3 (M quarters, 64 rows each)
    const int wn = wave & 1;       // 0..1 (N halves, 64 cols each)
    int bx, by;
    swz(bx, by);
    const int m0 = by * 256, n0 = bx * 128;

    const unsigned short* Ap;
    if (MODE == 0)      Ap = Abase + ((size_t)(m0 >> 11) * PADL + 3 + (m0 & 2047)) * DM;
    else if (MODE == 1) Ap = Abase + ((size_t)(m0 >> 11) * PADL + (m0 & 2047)) * DM;
    else if (MODE == 4) Ap = Abase + (size_t)blockIdx.z * DI * DI + (size_t)m0 * SA;
    else                Ap = Abase + (size_t)m0 * SA;
    const unsigned short* Bp = Bbase + (size_t)n0 * SB;

    const int strow = t >> 3;                           // 0..63
    const int gcs = ((t & 7) ^ (strow & 7)) * 8;        // inverse-swizzled src col
    const unsigned short* pA = Ap + (size_t)strow * SA + gcs;
    const unsigned short* pB = Bp + (size_t)strow * SB + gcs;
    const int ldsA = t * 8;
    const int ldsB = t * 8;

    const int am = lane & 15;
    const int qa = (lane >> 4) << 3;
    const int sw = (am & 7) << 3;
    const int c0 = qa ^ sw;
    const int c1 = (32 + qa) ^ sw;
    const int arow = (wm * 64 + am) * 64;
    const int brow = (wn * 64 + am) * 64;

    f32x4 acc[4][4];
#pragma unroll
    for (int i = 0; i < 4; ++i)
#pragma unroll
        for (int j = 0; j < 4; ++j)
            acc[i][j] = f32x4{0.f, 0.f, 0.f, 0.f};

    bf16x8 aX[4][2], bX[4][2], aY[4][2], bY[4][2];

    STAGE(0, 0);
    STAGE(1, 1);
    asm volatile("s_waitcnt vmcnt(6)" ::: "memory");
    __builtin_amdgcn_s_barrier();
    __builtin_amdgcn_sched_barrier(0);
    LOADF(aX, bX, 0);

#pragma unroll 1
    for (int it = 0; it < NI; ++it) {
        asm volatile("s_waitcnt lgkmcnt(0)" ::: "memory");
        __builtin_amdgcn_s_barrier();
        __builtin_amdgcn_sched_barrier(0);
        STAGE(0, 2 * it + 2);
        asm volatile("s_waitcnt vmcnt(6)" ::: "memory");
        __builtin_amdgcn_s_barrier();
        __builtin_amdgcn_sched_barrier(0);
        LOADF(aY, bY, 1);
        __builtin_amdgcn_s_setprio(1);
        MME(aX, bX);
        __builtin_amdgcn_s_setprio(0);
        asm volatile("s_waitcnt lgkmcnt(0)" ::: "memory");
        __builtin_amdgcn_s_barrier();
        __builtin_amdgcn_sched_barrier(0);
        STAGE(1, 2 * it + 3);
        asm volatile("s_waitcnt vmcnt(6)" ::: "memory");
        __builtin_amdgcn_s_barrier();
        __builtin_amdgcn_sched_barrier(0);
        LOADF(aX, bX, 0);
        __builtin_amdgcn_s_setprio(1);
        MME(aY, bY);
        __builtin_amdgcn_s_setprio(0);
    }

    asm volatile("s_waitcnt vmcnt(0) lgkmcnt(0)" ::: "memory");

    const int rq = (lane >> 4) << 2;
    const int er = m0 + wm * 64;
    const int ec = n0 + wn * 64 + am;
#pragma unroll
    for (int mi = 0; mi < 4; ++mi) {
#pragma unroll
        for (int nj = 0; nj < 4; ++nj) {
            int col = ec + nj * 16;
#pragma unroll
            for (int r = 0; r < 4; ++r) {
                int row = er + mi * 16 + rq + r;
                float v = acc[mi][nj][r];
                if (MODE == 0) {
                    out_bf[(size_t)row * DI + col] = f2b(v);
                } else if (MODE == 1) {
                    v += bias[col];
                    out_bf[(size_t)row * DI + col] = f2b(v);
                } else if (MODE == 2) {
                    v += bias[col];
                    float s = 1.f / (1.f + __expf(-v));
                    s = fminf(fmaxf(s, 1e-4f), 1.f);
                    out_bf[(size_t)row * DI + col] = f2b(s);
                } else { // MODE 4: Mbig[o][z*1024 + cm]
                    out_bf[(size_t)row * 4096 + (size_t)blockIdx.z * 1024 + col] = f2b(v);
                }
            }
        }
    }
}

// ---------------- B/C projection: MFMA split-K ----------------
__global__ void __launch_bounds__(256)
bc_mfma(const unsigned short* __restrict__ u,
        const unsigned short* __restrict__ w,
        float* __restrict__ pc)
{
    const int t = threadIdx.x;
    const int lane = t & 63;
    const int wave = t >> 6;
    const int ks = blockIdx.x;                    // 0..BCKS-1
    const int m0 = blockIdx.y * 128 + wave * 32;
    const int am = lane & 15, quad = lane >> 4;

    f32x4 acc[2][2];
#pragma unroll
    for (int i = 0; i < 2; ++i)
#pragma unroll
        for (int j = 0; j < 2; ++j)
            acc[i][j] = f32x4{0.f, 0.f, 0.f, 0.f};

    const int kbase = ks * (DI / BCKS);
    const unsigned short* ur0 = u + (size_t)(m0 + am) * DI;
    const unsigned short* ur1 = u + (size_t)(m0 + 16 + am) * DI;
    const unsigned short* wr0 = w + (size_t)am * DI;
    const unsigned short* wr1 = w + (size_t)(16 + am) * DI;
#pragma unroll 2
    for (int kk = 0; kk < DI / BCKS; kk += 32) {
        int k = kbase + kk + quad * 8;
        bf16x8 a0 = *(const bf16x8*)(ur0 + k);
        bf16x8 a1 = *(const bf16x8*)(ur1 + k);
        bf16x8 b0 = *(const bf16x8*)(wr0 + k);
        bf16x8 b1 = *(const bf16x8*)(wr1 + k);
        acc[0][0] = __builtin_amdgcn_mfma_f32_16x16x32_bf16(a0, b0, acc[0][0], 0, 0, 0);
        acc[0][1] = __builtin_amdgcn_mfma_f32_16x16x32_bf16(a0, b1, acc[0][1], 0, 0, 0);
        acc[1][0] = __builtin_amdgcn_mfma_f32_16x16x32_bf16(a1, b0, acc[1][0], 0, 0, 0);
        acc[1][1] = __builtin_amdgcn_mfma_f32_16x16x32_bf16(a1, b1, acc[1][1], 0, 0, 0);
    }
    float* base = pc + (size_t)ks * MTOT * 32;
#pragma unroll
    for (int i = 0; i < 2; ++i)
#pragma unroll
        for (int j = 0; j < 2; ++j)
#pragma unroll
            for (int r = 0; r < 4; ++r) {
                int row = m0 + i * 16 + quad * 4 + r;
                int col = j * 16 + am;
                base[(size_t)row * 32 + col] = acc[i][j][r];
            }
}

// ---------------- chunked selective scan ----------------
// scan_p1 reduces the bc split-K partials (pc) into LDS (bitwise the same
// ks-order sum as the old bc_reduce) and, from the dh==0 blocks, publishes
// the reduced bcf for scan_p3.
__global__ void __launch_bounds__(256)
scan_p1(const unsigned short* __restrict__ dt_bf,
        const unsigned short* __restrict__ u_bf,
        const float* __restrict__ pc,
        const float* __restrict__ A_log,
        float* __restrict__ Pbuf,
        float* __restrict__ Sbuf,
        float* __restrict__ bcf)
{
    const int t = threadIdx.x;
    const int blk = blockIdx.x;          // 1024 = c(64) x dh(8) x b(2)
    const int c  = blk & (NC - 1);
    const int dh = (blk >> 6) & 7;
    const int b  = blk >> 9;
    const int d  = dh * 256 + t;

    const size_t rowbase = (size_t)b * SEQL + (size_t)c * CL;

    __shared__ float sm[CL][32];
    for (int idx = t; idx < CL * 32; idx += 256) {
        int r = idx >> 5, n = idx & 31;
        size_t base = (rowbase + r) * 32 + n;
        float s = pc[base];
#pragma unroll
        for (int ks = 1; ks < BCKS; ++ks)
            s += pc[(size_t)ks * (MTOT * 32) + base];
        sm[r][n] = s;
        if (dh == 0) bcf[base] = s;
    }

    float Adn[16];
    {
        const float4* ar = (const float4*)(A_log + (size_t)d * DSN);
#pragma unroll
        for (int q = 0; q < 4; ++q) {
            float4 v = ar[q];
            Adn[q * 4 + 0] = -__expf(v.x);
            Adn[q * 4 + 1] = -__expf(v.y);
            Adn[q * 4 + 2] = -__expf(v.z);
            Adn[q * 4 + 3] = -__expf(v.w);
        }
    }
    float s[16], P[16];
#pragma unroll
    for (int n = 0; n < 16; ++n) { s[n] = 0.f; P[n] = 1.f; }

    __syncthreads();

    for (int l0 = 0; l0 < CL; l0 += 4) {
        float dt4[4], u4[4];
#pragma unroll
        for (int j = 0; j < 4; ++j) {
            size_t rb = rowbase + l0 + j;
            dt4[j] = b2f(dt_bf[rb * DI + d]);
            u4[j] = b2f(u_bf[rb * DI + d]);
        }
#pragma unroll
        for (int j = 0; j < 4; ++j) {
            const float4* Br = (const float4*)(&sm[l0 + j][0]);
            float Bn[16];
#pragma unroll
            for (int q = 0; q < 4; ++q) {
                float4 v = Br[q];
                Bn[q * 4 + 0] = v.x; Bn[q * 4 + 1] = v.y;
                Bn[q * 4 + 2] = v.z; Bn[q * 4 + 3] = v.w;
            }
            float dt = dt4[j];
            float dBu = dt * u4[j];
#pragma unroll
            for (int n = 0; n < 16; ++n) {
                float x = dt * Adn[n];
                x = fminf(fmaxf(x, -5.f), 5.f);
                float dA = __expf(x);
                P[n] *= dA;
                s[n] = dA * s[n] + (dBu * Bn[n] + 1e-6f);
            }
        }
    }
    size_t ob = (((size_t)c * BATCHN + b) * DI + d) * DSN;
#pragma unroll
    for (int q = 0; q < 4; ++q) {
        ((float4*)(Pbuf + ob))[q] = make_float4(P[q*4], P[q*4+1], P[q*4+2], P[q*4+3]);
        ((float4*)(Sbuf + ob))[q] = make_float4(s[q*4], s[q*4+1], s[q*4+2], s[q*4+3]);
    }
}

__global__ void __launch_bounds__(256)
scan_p2(const float* __restrict__ Pbuf,
        const float* __restrict__ Sbuf,
        float* __restrict__ Ibuf)
{
    const int i = blockIdx.x * 256 + threadIdx.x;  // (b*DI+d)*16+n, 65536
    const int stride = BATCHN * DI * DSN;          // 65536
    float s = 0.f;
    for (int c0 = 0; c0 < NC; c0 += 8) {
        float Pv[8], Sv[8];
#pragma unroll
        for (int j = 0; j < 8; ++j) {
            size_t idx = (size_t)(c0 + j) * stride + i;
            Pv[j] = Pbuf[idx];
            Sv[j] = Sbuf[idx];
        }
#pragma unroll
        for (int j = 0; j < 8; ++j) {
            size_t idx = (size_t)(c0 + j) * stride + i;
            Ibuf[idx] = s;
            s = Pv[j] * s + Sv[j];
        }
    }
}

__global__ void __launch_bounds__(256)
scan_p3(const unsigned short* __restrict__ dt_bf,
        const unsigned short* __restrict__ u_bf,
        const float* __restrict__ bcf,
        const unsigned short* __restrict__ z_bf,
        const float* __restrict__ A_log,
        const float* __restrict__ Dvec,
        const float* __restrict__ Ibuf,
        unsigned short* __restrict__ y_bf)
{
    const int t = threadIdx.x;
    const int blk = blockIdx.x;
    const int c  = blk & (NC - 1);
    const int dh = (blk >> 6) & 7;
    const int b  = blk >> 9;
    const int d  = dh * 256 + t;

    float Adn[16];
    {
        const float4* ar = (const float4*)(A_log + (size_t)d * DSN);
#pragma unroll
        for (int q = 0; q < 4; ++q) {
            float4 v = ar[q];
            Adn[q * 4 + 0] = -__expf(v.x);
            Adn[q * 4 + 1] = -__expf(v.y);
            Adn[q * 4 + 2] = -__expf(v.z);
            Adn[q * 4 + 3] = -__expf(v.w);
        }
    }
    const float Dd = Dvec[d];
    float s[16];
    {
        size_t ib = (((size_t)c * BATCHN + b) * DI + d) * DSN;
#pragma unroll
        for (int q = 0; q < 4; ++q) {
            float4 v = ((const float4*)(Ibuf + ib))[q];
            s[q * 4 + 0] = v.x; s[q * 4 + 1] = v.y;
            s[q * 4 + 2] = v.z; s[q * 4 + 3] = v.w;
        }
    }

    const size_t rowbase = (size_t)b * SEQL + (size_t)c * CL;
    for (int l0 = 0; l0 < CL; l0 += 4) {
        float dt4[4], u4[4], z4[4];
#pragma unroll
        for (int j = 0; j < 4; ++j) {
            size_t rb = rowbase + l0 + j;
            dt4[j] = b2f(dt_bf[rb * DI + d]);
            u4[j] = b2f(u_bf[rb * DI + d]);
            z4[j] = b2f(z_bf[rb * DI + d]);
        }
#pragma unroll
        for (int j = 0; j < 4; ++j) {
            size_t rb = rowbase + l0 + j;
            const float4* Br = (const float4*)(bcf + rb * 32);
            float Bn[16], Cn[16];
#pragma unroll
            for (int q = 0; q < 4; ++q) {
                float4 v = Br[q];
                Bn[q * 4 + 0] = v.x; Bn[q * 4 + 1] = v.y;
                Bn[q * 4 + 2] = v.z; Bn[q * 4 + 3] = v.w;
                float4 w = Br[q + 4];
                Cn[q * 4 + 0] = w.x; Cn[q * 4 + 1] = w.y;
                Cn[q * 4 + 2] = w.z; Cn[q * 4 + 3] = w.w;
            }
            float dt = dt4[j];
            float dBu = dt * u4[j];
            float y = 0.f;
#pragma unroll
            for (int n = 0; n < 16; ++n) {
                float x = dt * Adn[n];
                x = fminf(fmaxf(x, -5.f), 5.f);
                float dA = __expf(x);
                s[n] = dA * s[n] + (dBu * Bn[n] + 1e-6f);
                y += s[n] * Cn[n];
            }
            y += Dd * u4[j];
            float zz = z4[j];
            y *= zz / (1.f + __expf(-zz));
            y_bf[rb * DI + d] = f2b(y);
        }
    }
}

// ---------------- launch ----------------
// R5: workspace overlay. Early-phase buffers (xpad, ipz, Pt, wk, mk — all
// dead once conv/mk/z GEMMs complete) share memory with late-phase buffers
// (Pbuf, Sbuf, Ibuf, y — first written at scan_p1, which launches after dt).
// Every byte is written before read within one kernel_launch, so inter-
// iteration workspace poisoning cannot affect correctness. ws: ~203 -> ~131 MB.
extern "C" void kernel_launch(void* const* d_in, const int* in_sizes, int n_in,
                              void* d_out, int out_size, void* d_ws, size_t ws_size,
                              hipStream_t stream) {
    const float* x     = (const float*)d_in[0];
    const float* ipw   = (const float*)d_in[1];
    const float* convw = (const float*)d_in[2];
    const float* convb = (const float*)d_in[3];
    const float* dtw   = (const float*)d_in[4];
    const float* dtb   = (const float*)d_in[5];
    const float* alog  = (const float*)d_in[6];
    const float* dvec  = (const float*)d_in[7];
    const float* bw    = (const float*)d_in[8];
    const float* cwm   = (const float*)d_in[9];
    const float* ow    = (const float*)d_in[10];
    float* out = (float*)d_out;

    char* ws = (char*)d_ws;
    char* ov = ws;   // 67,121,152-byte overlay region
    // early overlay (lifetimes end at conv/mk/z):
    unsigned short* xpad   = (unsigned short*)(ov);               //  8,400,896
    unsigned short* ipz_bf = (unsigned short*)(ov + 8400896);     //  4,194,304
    unsigned short* Pt_bf  = (unsigned short*)(ov + 12595200);    //  4,194,304
    unsigned short* wk_bf  = (unsigned short*)(ov + 16789504);    // 33,554,432
    unsigned short* mk_bf  = (unsigned short*)(ov + 50343936);    // 16,777,216 (Mbig [2048][4096])
    // late overlay (first write at scan_p1 / scan_p2 / scan_p3):
    float*          Pbuf   = (float*)(ov);                        // 16,777,216
    float*          Sbuf   = (float*)(ov + 16777216);             // 16,777,216
    float*          Ibuf   = (float*)(ov + 33554432);             // 16,777,216
    unsigned short* y_bf   = (unsigned short*)(ov + 50331648);    // 16,777,216

    size_t off = 67121152;
    auto carve = [&](size_t bytes) {
        char* p = ws + off;
        off += (bytes + 255) & ~(size_t)255;
        return p;
    };
    unsigned short* dtw_bf = (unsigned short*)carve((size_t)DI * DI * 2);
    unsigned short* ow_bf  = (unsigned short*)carve((size_t)DM * DI * 2);
    unsigned short* bc_bf  = (unsigned short*)carve((size_t)2 * DSN * DI * 2);
    unsigned short* z_bf   = (unsigned short*)carve((size_t)MTOT * DI * 2);
    unsigned short* u_bf   = (unsigned short*)carve((size_t)MTOT * DI * 2);
    unsigned short* dt_bf  = (unsigned short*)carve((size_t)MTOT * DI * 2);
    float*          bc_f   = (float*)carve((size_t)MTOT * 2 * DSN * 4);
    float*          pc_f   = (float*)carve((size_t)BCKS * MTOT * 32 * 4);

    // all converts in one launch
    cvt_all<<<NB_CVT_ALL, 256, 0, stream>>>(x, convw, ipw, dtw, ow, bw, cwm,
                                            xpad, wk_bf, Pt_bf, ipz_bf, dtw_bf,
                                            ow_bf, bc_bf);

    // mk-fuse: Mbig[o][z*1024+cm] = (W_z @ P)[o][cm]
    gemm8<4><<<dim3(8, 8, 4), 512, 0, stream>>>(wk_bf, Pt_bf, nullptr, mk_bf, nullptr);
    // z-proj: z = x @ ipz^T
    gemm8<0><<<dim3(16, 16), 512, 0, stream>>>(xpad, ipz_bf, nullptr, z_bf, nullptr);
    // conv (fused, single K=4096 GEMM over xpad sliding window x Mbig^T)
    gemm8<1><<<dim3(16, 16), 512, 0, stream>>>(xpad, mk_bf, convb, u_bf, nullptr);
    // B/C projection: MFMA split-K (reduce fused into scan_p1)
    bc_mfma<<<dim3(BCKS, MTOT / 128), 256, 0, stream>>>(u_bf, bc_bf, pc_f);
    // dt projection + sigmoid/clip -> bf16
    gemm8<2><<<dim3(16, 16), 512, 0, stream>>>(u_bf, dtw_bf, dtb, dt_bf, nullptr);
    // chunked scan (p1 also reduces pc -> bcf)
    scan_p1<<<BATCHN * 8 * NC, 256, 0, stream>>>(dt_bf, u_bf, pc_f, alog, Pbuf, Sbuf, bc_f);
    scan_p2<<<BATCHN * DI * DSN / 256, 256, 0, stream>>>(Pbuf, Sbuf, Ibuf);
    scan_p3<<<BATCHN * 8 * NC, 256, 0, stream>>>(dt_bf, u_bf, bc_f, z_bf, alog, dvec, Ibuf, y_bf);
    // out projection
    gemm_bt<3><<<dim3(8, 32), 256, 0, stream>>>(y_bf, ow_bf, nullptr, nullptr, out, DI);
}